// Round 7
// baseline (515.084 us; speedup 1.0000x reference)
//
#include <hip/hip_runtime.h>

typedef __bf16 bf16x8 __attribute__((ext_vector_type(8)));
typedef float f32x4 __attribute__((ext_vector_type(4)));

__device__ __forceinline__ unsigned short f2bf(float f) {
  unsigned u = __builtin_bit_cast(unsigned, f);
  u += 0x7fffu + ((u >> 16) & 1u);
  return (unsigned short)(u >> 16);
}
__device__ __forceinline__ float bf2f(unsigned short h) {
  unsigned u = ((unsigned)h) << 16;
  return __builtin_bit_cast(float, u);
}
__device__ __forceinline__ void gload16(const void* g, void* l) {
  __builtin_amdgcn_global_load_lds((const __attribute__((address_space(1))) void*)g,
                                   (__attribute__((address_space(3))) void*)l, 16, 0, 0);
}

// ---------------- phase A ----------------

// xmn[b,t,k] = mean_n x[b,:,t,k]
__global__ __launch_bounds__(256) void k_xmn(const float* __restrict__ x, float* __restrict__ xmn) {
  int b = blockIdx.x / 12, t = blockIdx.x % 12;
  int k = threadIdx.x & 31, sl = threadIdx.x >> 5;
  const float* xp = x + (size_t)b * 786432 + (size_t)t * 32 + k;
  float s = 0.f;
  for (int i = 0; i < 256; ++i) {
    int n = (sl << 8) + i;
    s += xp[(size_t)n * 384];
  }
  __shared__ float red[8][32];
  red[sl][k] = s;
  __syncthreads();
  if (threadIdx.x < 32) {
    float tot = 0.f;
#pragma unroll
    for (int j = 0; j < 8; ++j) tot += red[j][threadIdx.x];
    xmn[(b * 12 + t) * 32 + threadIdx.x] = tot * (1.0f / 2048.0f);
  }
}

// Fused: per block (4 n-values): mean_t(x) -> @W_Q0 -> contract with W_QS rows
__global__ __launch_bounds__(256) void k_qs(const float* __restrict__ x,
                                            const float* __restrict__ W_Q0,
                                            const float* __restrict__ W_QS,
                                            float* __restrict__ pqs) {
  __shared__ __align__(16) float w0[1024];
  __shared__ float lm[2048];
  __shared__ float lq[2048];
  __shared__ float red[4][16][64];
  int tid = threadIdx.x;
#pragma unroll
  for (int i = 0; i < 4; ++i) w0[tid + i * 256] = W_Q0[tid + i * 256];
  int n0 = blockIdx.x * 4;
#pragma unroll
  for (int j = 0; j < 8; ++j) {
    int i = tid + j * 256;
    int b = i >> 7, r = i & 127;
    int n = n0 + (r >> 5), k = r & 31;
    const float* xp = x + ((size_t)(b * 2048 + n) * 12) * 32 + k;
    float s = 0.f;
#pragma unroll
    for (int t = 0; t < 12; ++t) s += xp[t * 32];
    lm[i] = s * (1.0f / 12.0f);
  }
  __syncthreads();
#pragma unroll
  for (int j = 0; j < 8; ++j) {
    int i = tid + j * 256;
    int br = i >> 5, q = i & 31;
    const float* mrow = &lm[br * 32];
    float a = 0.f;
#pragma unroll
    for (int k = 0; k < 32; ++k) a += mrow[k] * w0[k * 32 + q];
    lq[i] = a;
  }
  __syncthreads();
  int lane = tid & 63, wid = tid >> 6;
  float acc[16];
#pragma unroll
  for (int b = 0; b < 16; ++b) acc[b] = 0.f;
  for (int rl = 0; rl < 32; ++rl) {
    int r = wid * 32 + rl;
    float wv = W_QS[(size_t)(n0 * 32 + r) * 64 + lane];
#pragma unroll
    for (int b = 0; b < 16; ++b) acc[b] += lq[b * 128 + r] * wv;
  }
#pragma unroll
  for (int b = 0; b < 16; ++b) red[wid][b][lane] = acc[b];
  __syncthreads();
#pragma unroll
  for (int it = 0; it < 4; ++it) {
    int idx = tid + it * 256;
    float s = red[0][idx >> 6][idx & 63] + red[1][idx >> 6][idx & 63] +
              red[2][idx >> 6][idx & 63] + red[3][idx >> 6][idx & 63];
    pqs[(size_t)blockIdx.x * 1024 + idx] = s;
  }
}

// Fused tail: qs-reduce + qt + attn + ets  (one block per batch b)
__global__ __launch_bounds__(256) void k_post(const float* __restrict__ pqs,
                                              const float* __restrict__ xmn,
                                              const float* __restrict__ W_Q0,
                                              const float* __restrict__ W_QT,
                                              const float* __restrict__ K_T,
                                              const float* __restrict__ K_S,
                                              const float* __restrict__ V_T,
                                              const float* __restrict__ V_S,
                                              unsigned short* __restrict__ ets_bf) {
  const int b = blockIdx.x, tid = threadIdx.x;
  __shared__ float red[4][64];
  __shared__ float qs_s[64];
  __shared__ float qt_s[64];
  __shared__ float xp[384];
  __shared__ float at_s[8];

  {
    float s = 0.f;
    for (int c = tid >> 6; c < 512; c += 4) s += pqs[(size_t)c * 1024 + b * 64 + (tid & 63)];
    red[tid >> 6][tid & 63] = s;
  }
  for (int i = tid; i < 384; i += 256) {
    int t = i >> 5, q = i & 31;
    float a = 0.f;
#pragma unroll
    for (int k = 0; k < 32; ++k) a += xmn[(b * 12 + t) * 32 + k] * W_Q0[k * 32 + q];
    xp[i] = a;
  }
  __syncthreads();
  if (tid < 64) qs_s[tid] = red[0][tid] + red[1][tid] + red[2][tid] + red[3][tid];
  __syncthreads();
  if (tid < 64) {
    float q = 0.f;
    for (int i = 0; i < 384; ++i) q += xp[i] * W_QT[i * 64 + tid];
    qt_s[tid] = q;
  }
  __syncthreads();
  if (tid < 64) {
    int lane = tid;
    float qsv = qs_s[lane], qtv = qt_s[lane];
    float lt[4], ls[4];
#pragma unroll
    for (int h = 0; h < 4; ++h) {
      float p = qtv * K_T[h * 64 + lane];
#pragma unroll
      for (int off = 32; off > 0; off >>= 1) p += __shfl_xor(p, off);
      lt[h] = p;
      float p2 = qsv * K_S[h * 64 + lane];
#pragma unroll
      for (int off = 32; off > 0; off >>= 1) p2 += __shfl_xor(p2, off);
      ls[h] = p2;
    }
    if (lane == 0) {
      const float scale = 0.125f;
      float mt = fmaxf(fmaxf(lt[0], lt[1]), fmaxf(lt[2], lt[3]));
      float ms = fmaxf(fmaxf(ls[0], ls[1]), fmaxf(ls[2], ls[3]));
      float et[4], es[4], st = 0.f, ss = 0.f;
#pragma unroll
      for (int h = 0; h < 4; ++h) {
        et[h] = __expf((lt[h] - mt) * scale); st += et[h];
        es[h] = __expf((ls[h] - ms) * scale); ss += es[h];
      }
#pragma unroll
      for (int h = 0; h < 4; ++h) {
        at_s[h] = et[h] / st;
        at_s[4 + h] = es[h] / ss;
      }
    }
  }
  __syncthreads();
  float a0 = at_s[0], a1 = at_s[1], a2 = at_s[2], a3 = at_s[3];
  float s0 = at_s[4], s1 = at_s[5], s2 = at_s[6], s3 = at_s[7];
  for (int n = tid; n < 2048; n += 256) {
    float v[10];
#pragma unroll
    for (int c = 0; c < 10; ++c) {
      int o = n * 10 + c;
      v[c] = a0 * V_T[o] + a1 * V_T[20480 + o] + a2 * V_T[40960 + o] + a3 * V_T[61440 + o] +
             s0 * V_S[o] + s1 * V_S[20480 + o] + s2 * V_S[40960 + o] + s3 * V_S[61440 + o];
    }
    uint4 lo, hi;
    lo.x = (unsigned)f2bf(v[0]) | ((unsigned)f2bf(v[1]) << 16);
    lo.y = (unsigned)f2bf(v[2]) | ((unsigned)f2bf(v[3]) << 16);
    lo.z = (unsigned)f2bf(v[4]) | ((unsigned)f2bf(v[5]) << 16);
    lo.w = (unsigned)f2bf(v[6]) | ((unsigned)f2bf(v[7]) << 16);
    hi.x = (unsigned)f2bf(v[8]) | ((unsigned)f2bf(v[9]) << 16);
    hi.y = 0; hi.z = 0; hi.w = 0;
    size_t idx = (size_t)b * 2048 + n;
    *(uint4*)(ets_bf + idx * 16) = lo;
    *(uint4*)(ets_bf + idx * 16 + 8) = hi;
  }
}

// ---------------- phase B: MFMA adjacency + row softmax -> bf16 ----------------

__global__ __launch_bounds__(512, 4) void k_adj(const unsigned short* __restrict__ ets_bf,
                                                const float* __restrict__ dis,
                                                unsigned short* __restrict__ adj) {
  __shared__ __align__(16) unsigned char Bsh[65536];
  __shared__ float st_max[8][16];
  __shared__ float st_sum[8][16];
  __shared__ float rowmax_s[16];
  __shared__ float rowinv_s[16];

  const int tid = threadIdx.x;
  const int lane = tid & 63;
  const int w = tid >> 6;
  const int cl = lane & 15;
  const int g = lane >> 4;
  const int b = blockIdx.x >> 7;
  const int n0 = (blockIdx.x & 127) << 4;

  const unsigned char* gsrc = (const unsigned char*)(ets_bf + (size_t)b * 32768);
#pragma unroll
  for (int it = 0; it < 8; ++it)
    gload16(gsrc + it * 8192 + tid * 16, Bsh + it * 8192 + (w << 10));
  __syncthreads();

  uint4 araw = *(const uint4*)(ets_bf + ((size_t)b * 2048 + n0 + cl) * 16 + (g & 1) * 8);
  if (g >= 2) { araw.x = 0; araw.y = 0; araw.z = 0; araw.w = 0; }
  bf16x8 afrag = __builtin_bit_cast(bf16x8, araw);

  f32x4 acc[16];
  const int cbase = (w << 8) + cl;
#pragma unroll
  for (int n = 0; n < 16; ++n) {
    uint4 braw = *(const uint4*)(Bsh + (size_t)(cbase + n * 16) * 32 + (g & 1) * 16);
    if (g >= 2) { braw.x = 0; braw.y = 0; braw.z = 0; braw.w = 0; }
    bf16x8 bfrag = __builtin_bit_cast(bf16x8, braw);
    acc[n] = __builtin_amdgcn_mfma_f32_16x16x32_bf16(afrag, bfrag, (f32x4){0.f, 0.f, 0.f, 0.f},
                                                     0, 0, 0);
  }

  float mx[4] = {-1e30f, -1e30f, -1e30f, -1e30f};
  const float* dbase = dis + (size_t)(n0 + g * 4) * 2048 + (w << 8) + cl;
#pragma unroll
  for (int n = 0; n < 16; ++n) {
#pragma unroll
    for (int j = 0; j < 4; ++j) {
      float s = fmaxf(acc[n][j] + dbase[(size_t)j * 2048 + n * 16], 0.f);
      acc[n][j] = s;
      mx[j] = fmaxf(mx[j], s);
    }
  }
#pragma unroll
  for (int j = 0; j < 4; ++j) {
    mx[j] = fmaxf(mx[j], __shfl_xor(mx[j], 1));
    mx[j] = fmaxf(mx[j], __shfl_xor(mx[j], 2));
    mx[j] = fmaxf(mx[j], __shfl_xor(mx[j], 4));
    mx[j] = fmaxf(mx[j], __shfl_xor(mx[j], 8));
  }
  if (cl == 0) {
#pragma unroll
    for (int j = 0; j < 4; ++j) st_max[w][g * 4 + j] = mx[j];
  }
  __syncthreads();
  if (tid < 16) {
    float m = st_max[0][tid];
#pragma unroll
    for (int ww = 1; ww < 8; ++ww) m = fmaxf(m, st_max[ww][tid]);
    rowmax_s[tid] = m;
  }
  __syncthreads();

  float rm[4], sm[4] = {0.f, 0.f, 0.f, 0.f};
#pragma unroll
  for (int j = 0; j < 4; ++j) rm[j] = rowmax_s[g * 4 + j];
#pragma unroll
  for (int n = 0; n < 16; ++n) {
#pragma unroll
    for (int j = 0; j < 4; ++j) {
      float e = __expf(acc[n][j] - rm[j]);
      acc[n][j] = e;
      sm[j] += e;
    }
  }
#pragma unroll
  for (int j = 0; j < 4; ++j) {
    sm[j] += __shfl_xor(sm[j], 1);
    sm[j] += __shfl_xor(sm[j], 2);
    sm[j] += __shfl_xor(sm[j], 4);
    sm[j] += __shfl_xor(sm[j], 8);
  }
  if (cl == 0) {
#pragma unroll
    for (int j = 0; j < 4; ++j) st_sum[w][g * 4 + j] = sm[j];
  }
  __syncthreads();
  if (tid < 16) {
    float s = st_sum[0][tid];
#pragma unroll
    for (int ww = 1; ww < 8; ++ww) s += st_sum[ww][tid];
    rowinv_s[tid] = 1.0f / s;
  }
  __syncthreads();

  unsigned short* Tw = (unsigned short*)Bsh + (w << 12);
  float inv[4];
#pragma unroll
  for (int j = 0; j < 4; ++j) inv[j] = rowinv_s[g * 4 + j];
#pragma unroll
  for (int n = 0; n < 16; ++n) {
#pragma unroll
    for (int j = 0; j < 4; ++j)
      Tw[(g * 4 + j) * 256 + n * 16 + cl] = f2bf(acc[n][j] * inv[j]);
  }
  __syncthreads();

  unsigned short* obase = adj + ((size_t)b * 2048 + n0) * 2048 + (w << 8);
#pragma unroll
  for (int r = 0; r < 16; ++r) {
    uint2 v = *(const uint2*)(Tw + r * 256 + lane * 4);
    *(uint2*)(obase + (size_t)r * 2048 + lane * 4) = v;
  }
}

// ---------------- phase C producers ----------------

__device__ __forceinline__ void compute_mat(const float* w, const float* xv, float* out) {
  float4 a[8];
#pragma unroll
  for (int i = 0; i < 8; ++i) a[i] = make_float4(0.f, 0.f, 0.f, 0.f);
#pragma unroll
  for (int k = 0; k < 32; ++k) {
    float xk = xv[k];
#pragma unroll
    for (int d4 = 0; d4 < 8; ++d4) {
      float4 wv = ((const float4*)(w + k * 32))[d4];
      a[d4].x += xk * wv.x; a[d4].y += xk * wv.y; a[d4].z += xk * wv.z; a[d4].w += xk * wv.w;
    }
  }
#pragma unroll
  for (int d4 = 0; d4 < 8; ++d4) {
    out[4 * d4 + 0] = a[d4].x; out[4 * d4 + 1] = a[d4].y;
    out[4 * d4 + 2] = a[d4].z; out[4 * d4 + 3] = a[d4].w;
  }
}

__device__ __forceinline__ void store32bf(unsigned short* p, const float* v) {
#pragma unroll
  for (int i = 0; i < 4; ++i) {
    uint4 u;
    u.x = (unsigned)f2bf(v[8 * i + 0]) | ((unsigned)f2bf(v[8 * i + 1]) << 16);
    u.y = (unsigned)f2bf(v[8 * i + 2]) | ((unsigned)f2bf(v[8 * i + 3]) << 16);
    u.z = (unsigned)f2bf(v[8 * i + 4]) | ((unsigned)f2bf(v[8 * i + 5]) << 16);
    u.w = (unsigned)f2bf(v[8 * i + 6]) | ((unsigned)f2bf(v[8 * i + 7]) << 16);
    ((uint4*)p)[i] = u;
  }
}

__global__ __launch_bounds__(256) void k_zb(const float* __restrict__ x,
                                            const float* __restrict__ W2,
                                            const float* __restrict__ Ws0,
                                            const float* __restrict__ Ws1,
                                            unsigned short* __restrict__ z0T,
                                            unsigned short* __restrict__ bias0,
                                            unsigned short* __restrict__ bias1) {
  __shared__ __align__(16) float w[3][1024];
  int tid = threadIdx.x;
  for (int i = tid; i < 1024; i += 256) {
    w[0][i] = W2[i]; w[1][i] = Ws0[i]; w[2][i] = Ws1[i];
  }
  __syncthreads();
  int bx = blockIdx.x;
  int b = bx / 96, r = bx % 96, t = r >> 3, mc = r & 7;
  int m = (mc << 8) + tid;
  const float4* xp = (const float4*)(x + (((size_t)(b * 2048 + m)) * 12 + t) * 32);
  float xv[32];
#pragma unroll
  for (int i = 0; i < 8; ++i) {
    float4 v = xp[i];
    xv[4 * i + 0] = v.x; xv[4 * i + 1] = v.y; xv[4 * i + 2] = v.z; xv[4 * i + 3] = v.w;
  }
  float out[32];
  compute_mat(w[0], xv, out);
  unsigned short* zp = z0T + (size_t)b * 786432 + (size_t)(t * 32) * 2048 + m;
#pragma unroll
  for (int d = 0; d < 32; ++d) zp[(size_t)d * 2048] = f2bf(out[d]);
  size_t bb = ((size_t)(b * 2048 + m)) * 384 + t * 32;
  compute_mat(w[1], xv, out);
  store32bf(bias0 + bb, out);
  compute_mat(w[2], xv, out);
  store32bf(bias1 + bb, out);
}

// ---------------- phase C: adj @ z (+bias) MFMA GEMM ----------------
// 128x192 tile, BK=64; A: global_load_lds double-buffer (LDS 32KB, swizzled);
// B: DIRECT global->VGPR (L2-resident), double-buffered per kk; counted vmcnt.

template <int OUT_F32>
__global__ __launch_bounds__(256, 2) void gemm_adj(const unsigned short* __restrict__ adj,
                                                   const unsigned short* __restrict__ Bt,
                                                   const unsigned short* __restrict__ bias,
                                                   void* __restrict__ outp) {
  const int tid = threadIdx.x;
  const int lane = tid & 63;
  const int wid = tid >> 6;
  const int wr = wid >> 1, wc = wid & 1;
  // XCD-bijective swizzle: 512 blocks = 8 XCDs x 64; each XCD owns 2 whole batches
  const int orig = blockIdx.x;
  const int wg = (orig & 7) * 64 + (orig >> 3);
  const int b = wg >> 5;
  const int w32 = wg & 31;
  const int m0 = ((w32 >> 1) & 15) << 7;
  const int c0 = (w32 & 1) * 192;

  // A only in LDS: 2 x (128 x 64 bf16 = 16KB)
  __shared__ __align__(16) unsigned char smem[32768];

  const unsigned short* aBase = adj + ((size_t)b << 22);
  const unsigned short* bBase = Bt + (size_t)b * 786432;

  // A staging: thread -> row (tid>>3) (+32/64/96), chunk (tid&7) inverse-swizzled
  const int jx = ((tid & 7) ^ ((tid >> 3) & 7)) << 3;
  const unsigned short* gA = aBase + (size_t)(m0 + (tid >> 3)) * 2048 + jx;

  // A ds_read offsets (swizzled)
  int aoff[2][4];
#pragma unroll
  for (int kk = 0; kk < 2; ++kk) {
    int c = kk * 4 + (lane >> 4);
#pragma unroll
    for (int f = 0; f < 4; ++f) {
      int rA = wr * 64 + f * 16 + (lane & 15);
      aoff[kk][f] = rA * 128 + ((c ^ (rA & 7)) << 4);
    }
  }

  // B direct-global per-lane base: col = c0 + wc*96 + n*16 + (lane&15), k-off (lane>>4)*8
  const unsigned short* gB =
      bBase + (size_t)(c0 + wc * 96 + (lane & 15)) * 2048 + ((lane >> 4) << 3);

  f32x4 acc[4][6] = {};
  bf16x8 b0[6], b1[6];

#define STAGEA(BUF, KT)                                                \
  {                                                                    \
    gload16(gA + (KT) * 64, smem + (BUF) + tid * 16);                  \
    gload16(gA + 65536 + (KT) * 64, smem + (BUF) + 4096 + tid * 16);   \
    gload16(gA + 131072 + (KT) * 64, smem + (BUF) + 8192 + tid * 16);  \
    gload16(gA + 196608 + (KT) * 64, smem + (BUF) + 12288 + tid * 16); \
  }
#define LOADB(DST, KT, KK)                                                        \
  {                                                                               \
    _Pragma("unroll") for (int n = 0; n < 6; ++n) DST[n] =                        \
        *(const bf16x8*)(gB + (size_t)n * 32768 + (KT) * 64 + (KK) * 32);         \
  }

  // prologue
  STAGEA(0, 0);
  LOADB(b0, 0, 0);

  int cur = 0;
  for (int kt = 0; kt < 32; ++kt) {
    const int nxt = cur ^ 16384;
    if (kt < 31) {
      STAGEA(nxt, kt + 1);       // 4 vmem
      LOADB(b1, kt, 1);          // 6 vmem
      // wait A(kt) + B(kt,kk0) landed; the 10 just issued stay in flight
      asm volatile("s_waitcnt vmcnt(10)" ::: "memory");
    } else {
      LOADB(b1, kt, 1);
      asm volatile("s_waitcnt vmcnt(6)" ::: "memory");
    }
    __builtin_amdgcn_s_barrier();
    // kk0: ds_read A + MFMA against b0
    {
      bf16x8 af[4];
#pragma unroll
      for (int f = 0; f < 4; ++f) af[f] = *(const bf16x8*)(smem + cur + aoff[0][f]);
#pragma unroll
      for (int m = 0; m < 4; ++m)
#pragma unroll
        for (int n = 0; n < 6; ++n)
          acc[m][n] = __builtin_amdgcn_mfma_f32_16x16x32_bf16(af[m], b0[n], acc[m][n], 0, 0, 0);
    }
    if (kt < 31) LOADB(b0, kt + 1, 0);  // prefetch next tile's kk0 during kk1 compute
    // kk1: ds_read A + MFMA against b1 (compiler inserts the vmcnt for b1)
    {
      bf16x8 af[4];
#pragma unroll
      for (int f = 0; f < 4; ++f) af[f] = *(const bf16x8*)(smem + cur + aoff[1][f]);
#pragma unroll
      for (int m = 0; m < 4; ++m)
#pragma unroll
        for (int n = 0; n < 6; ++n)
          acc[m][n] = __builtin_amdgcn_mfma_f32_16x16x32_bf16(af[m], b1[n], acc[m][n], 0, 0, 0);
    }
    __builtin_amdgcn_s_barrier();  // protect cur buffer before next iter's STAGEA overwrites
    cur = nxt;
  }
#undef STAGEA
#undef LOADB

  const int cl = lane & 15;
  const int r4 = (lane >> 4) << 2;
  const unsigned short* bi = bias + (size_t)b * 786432;
  if (OUT_F32) {
    float* o = (float*)outp + (size_t)b * 786432;
#pragma unroll
    for (int m = 0; m < 4; ++m) {
      int row0 = m0 + wr * 64 + m * 16 + r4;
#pragma unroll
      for (int n = 0; n < 6; ++n) {
        int col = c0 + wc * 96 + n * 16 + cl;
#pragma unroll
        for (int r = 0; r < 4; ++r) {
          int row = row0 + r;
          o[(size_t)row * 384 + col] = acc[m][n][r] + bf2f(bi[(size_t)row * 384 + col]);
        }
      }
    }
  } else {
    unsigned short* o = (unsigned short*)outp + (size_t)b * 786432;
#pragma unroll
    for (int m = 0; m < 4; ++m) {
      int row0 = m0 + wr * 64 + m * 16 + r4;
#pragma unroll
      for (int n = 0; n < 6; ++n) {
        int col = c0 + wc * 96 + n * 16 + cl;
        ushort4 pk;
        pk.x = f2bf(acc[m][n][0] + bf2f(bi[(size_t)(row0 + 0) * 384 + col]));
        pk.y = f2bf(acc[m][n][1] + bf2f(bi[(size_t)(row0 + 1) * 384 + col]));
        pk.z = f2bf(acc[m][n][2] + bf2f(bi[(size_t)(row0 + 2) * 384 + col]));
        pk.w = f2bf(acc[m][n][3] + bf2f(bi[(size_t)(row0 + 3) * 384 + col]));
        *(ushort4*)(o + (size_t)col * 2048 + row0) = pk;
      }
    }
  }
}

// ---------------- launch ----------------

extern "C" void kernel_launch(void* const* d_in, const int* in_sizes, int n_in,
                              void* d_out, int out_size, void* d_ws, size_t ws_size,
                              hipStream_t stream) {
  const float* x = (const float*)d_in[0];
  const float* dis = (const float*)d_in[1];
  const float* K_S = (const float*)d_in[2];
  const float* V_S = (const float*)d_in[3];
  const float* K_T = (const float*)d_in[4];
  const float* V_T = (const float*)d_in[5];
  const float* W_Q0 = (const float*)d_in[6];
  const float* W_QS = (const float*)d_in[7];
  const float* W_QT = (const float*)d_in[8];
  const float* W2 = (const float*)d_in[9];
  const float* W_s0 = (const float*)d_in[10];
  const float* W_s1 = (const float*)d_in[11];

  char* ws = (char*)d_ws;
  float* xmn = (float*)(ws + 0);                             //     24,576 B
  float* pqs = (float*)(ws + 28672);                         //  2,097,152 B
  unsigned short* ets_bf = (unsigned short*)(ws + 2130432);  //  1,048,576 B
  unsigned short* adj = (unsigned short*)(ws + 3179008);     // 134,217,728 B
  unsigned short* z0T = (unsigned short*)(ws + 137396736);   // 25,165,824 B
  unsigned short* z1T = (unsigned short*)(ws + 162562560);   // 25,165,824 B
  unsigned short* bias0 = (unsigned short*)(ws + 187728384); // 25,165,824 B
  unsigned short* bias1 = (unsigned short*)(ws + 212894208); // 25,165,824 B

  k_xmn<<<192, 256, 0, stream>>>(x, xmn);
  k_qs<<<512, 256, 0, stream>>>(x, W_Q0, W_QS, pqs);
  k_post<<<16, 256, 0, stream>>>(pqs, xmn, W_Q0, W_QT, K_T, K_S, V_T, V_S, ets_bf);
  k_adj<<<2048, 512, 0, stream>>>(ets_bf, dis, adj);
  k_zb<<<1536, 256, 0, stream>>>(x, W2, W_s0, W_s1, z0T, bias0, bias1);
  gemm_adj<0><<<512, 256, 0, stream>>>(adj, z0T, bias0, (void*)z1T);
  gemm_adj<1><<<512, 256, 0, stream>>>(adj, z1T, bias1, d_out);
}

// Round 8
// 404.666 us; speedup vs baseline: 1.2729x; 1.2729x over previous
//
#include <hip/hip_runtime.h>

typedef __bf16 bf16x8 __attribute__((ext_vector_type(8)));
typedef float f32x4 __attribute__((ext_vector_type(4)));

__device__ __forceinline__ unsigned short f2bf(float f) {
  unsigned u = __builtin_bit_cast(unsigned, f);
  u += 0x7fffu + ((u >> 16) & 1u);
  return (unsigned short)(u >> 16);
}
__device__ __forceinline__ float bf2f(unsigned short h) {
  unsigned u = ((unsigned)h) << 16;
  return __builtin_bit_cast(float, u);
}
__device__ __forceinline__ void gload16(const void* g, void* l) {
  __builtin_amdgcn_global_load_lds((const __attribute__((address_space(1))) void*)g,
                                   (__attribute__((address_space(3))) void*)l, 16, 0, 0);
}

// ---------------- phase A ----------------

// xmn[b,t,k] = mean_n x[b,:,t,k]
__global__ __launch_bounds__(256) void k_xmn(const float* __restrict__ x, float* __restrict__ xmn) {
  int b = blockIdx.x / 12, t = blockIdx.x % 12;
  int k = threadIdx.x & 31, sl = threadIdx.x >> 5;
  const float* xp = x + (size_t)b * 786432 + (size_t)t * 32 + k;
  float s = 0.f;
  for (int i = 0; i < 256; ++i) {
    int n = (sl << 8) + i;
    s += xp[(size_t)n * 384];
  }
  __shared__ float red[8][32];
  red[sl][k] = s;
  __syncthreads();
  if (threadIdx.x < 32) {
    float tot = 0.f;
#pragma unroll
    for (int j = 0; j < 8; ++j) tot += red[j][threadIdx.x];
    xmn[(b * 12 + t) * 32 + threadIdx.x] = tot * (1.0f / 2048.0f);
  }
}

// Fused: per block (4 n-values): mean_t(x) -> @W_Q0 -> contract with W_QS rows
__global__ __launch_bounds__(256) void k_qs(const float* __restrict__ x,
                                            const float* __restrict__ W_Q0,
                                            const float* __restrict__ W_QS,
                                            float* __restrict__ pqs) {
  __shared__ __align__(16) float w0[1024];
  __shared__ float lm[2048];
  __shared__ float lq[2048];
  __shared__ float red[4][16][64];
  int tid = threadIdx.x;
#pragma unroll
  for (int i = 0; i < 4; ++i) w0[tid + i * 256] = W_Q0[tid + i * 256];
  int n0 = blockIdx.x * 4;
#pragma unroll
  for (int j = 0; j < 8; ++j) {
    int i = tid + j * 256;
    int b = i >> 7, r = i & 127;
    int n = n0 + (r >> 5), k = r & 31;
    const float* xp = x + ((size_t)(b * 2048 + n) * 12) * 32 + k;
    float s = 0.f;
#pragma unroll
    for (int t = 0; t < 12; ++t) s += xp[t * 32];
    lm[i] = s * (1.0f / 12.0f);
  }
  __syncthreads();
#pragma unroll
  for (int j = 0; j < 8; ++j) {
    int i = tid + j * 256;
    int br = i >> 5, q = i & 31;
    const float* mrow = &lm[br * 32];
    float a = 0.f;
#pragma unroll
    for (int k = 0; k < 32; ++k) a += mrow[k] * w0[k * 32 + q];
    lq[i] = a;
  }
  __syncthreads();
  int lane = tid & 63, wid = tid >> 6;
  float acc[16];
#pragma unroll
  for (int b = 0; b < 16; ++b) acc[b] = 0.f;
  for (int rl = 0; rl < 32; ++rl) {
    int r = wid * 32 + rl;
    float wv = W_QS[(size_t)(n0 * 32 + r) * 64 + lane];
#pragma unroll
    for (int b = 0; b < 16; ++b) acc[b] += lq[b * 128 + r] * wv;
  }
#pragma unroll
  for (int b = 0; b < 16; ++b) red[wid][b][lane] = acc[b];
  __syncthreads();
#pragma unroll
  for (int it = 0; it < 4; ++it) {
    int idx = tid + it * 256;
    float s = red[0][idx >> 6][idx & 63] + red[1][idx >> 6][idx & 63] +
              red[2][idx >> 6][idx & 63] + red[3][idx >> 6][idx & 63];
    pqs[(size_t)blockIdx.x * 1024 + idx] = s;
  }
}

// Fused tail: qs-reduce + qt + attn + ets  (one block per batch b)
__global__ __launch_bounds__(256) void k_post(const float* __restrict__ pqs,
                                              const float* __restrict__ xmn,
                                              const float* __restrict__ W_Q0,
                                              const float* __restrict__ W_QT,
                                              const float* __restrict__ K_T,
                                              const float* __restrict__ K_S,
                                              const float* __restrict__ V_T,
                                              const float* __restrict__ V_S,
                                              unsigned short* __restrict__ ets_bf) {
  const int b = blockIdx.x, tid = threadIdx.x;
  __shared__ float red[4][64];
  __shared__ float qs_s[64];
  __shared__ float qt_s[64];
  __shared__ float xp[384];
  __shared__ float at_s[8];

  {
    float s = 0.f;
    for (int c = tid >> 6; c < 512; c += 4) s += pqs[(size_t)c * 1024 + b * 64 + (tid & 63)];
    red[tid >> 6][tid & 63] = s;
  }
  for (int i = tid; i < 384; i += 256) {
    int t = i >> 5, q = i & 31;
    float a = 0.f;
#pragma unroll
    for (int k = 0; k < 32; ++k) a += xmn[(b * 12 + t) * 32 + k] * W_Q0[k * 32 + q];
    xp[i] = a;
  }
  __syncthreads();
  if (tid < 64) qs_s[tid] = red[0][tid] + red[1][tid] + red[2][tid] + red[3][tid];
  __syncthreads();
  if (tid < 64) {
    float q = 0.f;
    for (int i = 0; i < 384; ++i) q += xp[i] * W_QT[i * 64 + tid];
    qt_s[tid] = q;
  }
  __syncthreads();
  if (tid < 64) {
    int lane = tid;
    float qsv = qs_s[lane], qtv = qt_s[lane];
    float lt[4], ls[4];
#pragma unroll
    for (int h = 0; h < 4; ++h) {
      float p = qtv * K_T[h * 64 + lane];
#pragma unroll
      for (int off = 32; off > 0; off >>= 1) p += __shfl_xor(p, off);
      lt[h] = p;
      float p2 = qsv * K_S[h * 64 + lane];
#pragma unroll
      for (int off = 32; off > 0; off >>= 1) p2 += __shfl_xor(p2, off);
      ls[h] = p2;
    }
    if (lane == 0) {
      const float scale = 0.125f;
      float mt = fmaxf(fmaxf(lt[0], lt[1]), fmaxf(lt[2], lt[3]));
      float ms = fmaxf(fmaxf(ls[0], ls[1]), fmaxf(ls[2], ls[3]));
      float et[4], es[4], st = 0.f, ss = 0.f;
#pragma unroll
      for (int h = 0; h < 4; ++h) {
        et[h] = __expf((lt[h] - mt) * scale); st += et[h];
        es[h] = __expf((ls[h] - ms) * scale); ss += es[h];
      }
#pragma unroll
      for (int h = 0; h < 4; ++h) {
        at_s[h] = et[h] / st;
        at_s[4 + h] = es[h] / ss;
      }
    }
  }
  __syncthreads();
  float a0 = at_s[0], a1 = at_s[1], a2 = at_s[2], a3 = at_s[3];
  float s0 = at_s[4], s1 = at_s[5], s2 = at_s[6], s3 = at_s[7];
  for (int n = tid; n < 2048; n += 256) {
    float v[10];
#pragma unroll
    for (int c = 0; c < 10; ++c) {
      int o = n * 10 + c;
      v[c] = a0 * V_T[o] + a1 * V_T[20480 + o] + a2 * V_T[40960 + o] + a3 * V_T[61440 + o] +
             s0 * V_S[o] + s1 * V_S[20480 + o] + s2 * V_S[40960 + o] + s3 * V_S[61440 + o];
    }
    uint4 lo, hi;
    lo.x = (unsigned)f2bf(v[0]) | ((unsigned)f2bf(v[1]) << 16);
    lo.y = (unsigned)f2bf(v[2]) | ((unsigned)f2bf(v[3]) << 16);
    lo.z = (unsigned)f2bf(v[4]) | ((unsigned)f2bf(v[5]) << 16);
    lo.w = (unsigned)f2bf(v[6]) | ((unsigned)f2bf(v[7]) << 16);
    hi.x = (unsigned)f2bf(v[8]) | ((unsigned)f2bf(v[9]) << 16);
    hi.y = 0; hi.z = 0; hi.w = 0;
    size_t idx = (size_t)b * 2048 + n;
    *(uint4*)(ets_bf + idx * 16) = lo;
    *(uint4*)(ets_bf + idx * 16 + 8) = hi;
  }
}

// ---------------- phase B: MFMA adjacency + row softmax -> bf16 ----------------

__global__ __launch_bounds__(512, 4) void k_adj(const unsigned short* __restrict__ ets_bf,
                                                const float* __restrict__ dis,
                                                unsigned short* __restrict__ adj) {
  __shared__ __align__(16) unsigned char Bsh[65536];
  __shared__ float st_max[8][16];
  __shared__ float st_sum[8][16];
  __shared__ float rowmax_s[16];
  __shared__ float rowinv_s[16];

  const int tid = threadIdx.x;
  const int lane = tid & 63;
  const int w = tid >> 6;
  const int cl = lane & 15;
  const int g = lane >> 4;
  const int b = blockIdx.x >> 7;
  const int n0 = (blockIdx.x & 127) << 4;

  const unsigned char* gsrc = (const unsigned char*)(ets_bf + (size_t)b * 32768);
#pragma unroll
  for (int it = 0; it < 8; ++it)
    gload16(gsrc + it * 8192 + tid * 16, Bsh + it * 8192 + (w << 10));
  __syncthreads();

  uint4 araw = *(const uint4*)(ets_bf + ((size_t)b * 2048 + n0 + cl) * 16 + (g & 1) * 8);
  if (g >= 2) { araw.x = 0; araw.y = 0; araw.z = 0; araw.w = 0; }
  bf16x8 afrag = __builtin_bit_cast(bf16x8, araw);

  f32x4 acc[16];
  const int cbase = (w << 8) + cl;
#pragma unroll
  for (int n = 0; n < 16; ++n) {
    uint4 braw = *(const uint4*)(Bsh + (size_t)(cbase + n * 16) * 32 + (g & 1) * 16);
    if (g >= 2) { braw.x = 0; braw.y = 0; braw.z = 0; braw.w = 0; }
    bf16x8 bfrag = __builtin_bit_cast(bf16x8, braw);
    acc[n] = __builtin_amdgcn_mfma_f32_16x16x32_bf16(afrag, bfrag, (f32x4){0.f, 0.f, 0.f, 0.f},
                                                     0, 0, 0);
  }

  float mx[4] = {-1e30f, -1e30f, -1e30f, -1e30f};
  const float* dbase = dis + (size_t)(n0 + g * 4) * 2048 + (w << 8) + cl;
#pragma unroll
  for (int n = 0; n < 16; ++n) {
#pragma unroll
    for (int j = 0; j < 4; ++j) {
      float s = fmaxf(acc[n][j] + dbase[(size_t)j * 2048 + n * 16], 0.f);
      acc[n][j] = s;
      mx[j] = fmaxf(mx[j], s);
    }
  }
#pragma unroll
  for (int j = 0; j < 4; ++j) {
    mx[j] = fmaxf(mx[j], __shfl_xor(mx[j], 1));
    mx[j] = fmaxf(mx[j], __shfl_xor(mx[j], 2));
    mx[j] = fmaxf(mx[j], __shfl_xor(mx[j], 4));
    mx[j] = fmaxf(mx[j], __shfl_xor(mx[j], 8));
  }
  if (cl == 0) {
#pragma unroll
    for (int j = 0; j < 4; ++j) st_max[w][g * 4 + j] = mx[j];
  }
  __syncthreads();
  if (tid < 16) {
    float m = st_max[0][tid];
#pragma unroll
    for (int ww = 1; ww < 8; ++ww) m = fmaxf(m, st_max[ww][tid]);
    rowmax_s[tid] = m;
  }
  __syncthreads();

  float rm[4], sm[4] = {0.f, 0.f, 0.f, 0.f};
#pragma unroll
  for (int j = 0; j < 4; ++j) rm[j] = rowmax_s[g * 4 + j];
#pragma unroll
  for (int n = 0; n < 16; ++n) {
#pragma unroll
    for (int j = 0; j < 4; ++j) {
      float e = __expf(acc[n][j] - rm[j]);
      acc[n][j] = e;
      sm[j] += e;
    }
  }
#pragma unroll
  for (int j = 0; j < 4; ++j) {
    sm[j] += __shfl_xor(sm[j], 1);
    sm[j] += __shfl_xor(sm[j], 2);
    sm[j] += __shfl_xor(sm[j], 4);
    sm[j] += __shfl_xor(sm[j], 8);
  }
  if (cl == 0) {
#pragma unroll
    for (int j = 0; j < 4; ++j) st_sum[w][g * 4 + j] = sm[j];
  }
  __syncthreads();
  if (tid < 16) {
    float s = st_sum[0][tid];
#pragma unroll
    for (int ww = 1; ww < 8; ++ww) s += st_sum[ww][tid];
    rowinv_s[tid] = 1.0f / s;
  }
  __syncthreads();

  unsigned short* Tw = (unsigned short*)Bsh + (w << 12);
  float inv[4];
#pragma unroll
  for (int j = 0; j < 4; ++j) inv[j] = rowinv_s[g * 4 + j];
#pragma unroll
  for (int n = 0; n < 16; ++n) {
#pragma unroll
    for (int j = 0; j < 4; ++j)
      Tw[(g * 4 + j) * 256 + n * 16 + cl] = f2bf(acc[n][j] * inv[j]);
  }
  __syncthreads();

  unsigned short* obase = adj + ((size_t)b * 2048 + n0) * 2048 + (w << 8);
#pragma unroll
  for (int r = 0; r < 16; ++r) {
    uint2 v = *(const uint2*)(Tw + r * 256 + lane * 4);
    *(uint2*)(obase + (size_t)r * 2048 + lane * 4) = v;
  }
}

// ---------------- phase C producers ----------------

__device__ __forceinline__ void compute_mat(const float* w, const float* xv, float* out) {
  float4 a[8];
#pragma unroll
  for (int i = 0; i < 8; ++i) a[i] = make_float4(0.f, 0.f, 0.f, 0.f);
#pragma unroll
  for (int k = 0; k < 32; ++k) {
    float xk = xv[k];
#pragma unroll
    for (int d4 = 0; d4 < 8; ++d4) {
      float4 wv = ((const float4*)(w + k * 32))[d4];
      a[d4].x += xk * wv.x; a[d4].y += xk * wv.y; a[d4].z += xk * wv.z; a[d4].w += xk * wv.w;
    }
  }
#pragma unroll
  for (int d4 = 0; d4 < 8; ++d4) {
    out[4 * d4 + 0] = a[d4].x; out[4 * d4 + 1] = a[d4].y;
    out[4 * d4 + 2] = a[d4].z; out[4 * d4 + 3] = a[d4].w;
  }
}

__device__ __forceinline__ void store32bf(unsigned short* p, const float* v) {
#pragma unroll
  for (int i = 0; i < 4; ++i) {
    uint4 u;
    u.x = (unsigned)f2bf(v[8 * i + 0]) | ((unsigned)f2bf(v[8 * i + 1]) << 16);
    u.y = (unsigned)f2bf(v[8 * i + 2]) | ((unsigned)f2bf(v[8 * i + 3]) << 16);
    u.z = (unsigned)f2bf(v[8 * i + 4]) | ((unsigned)f2bf(v[8 * i + 5]) << 16);
    u.w = (unsigned)f2bf(v[8 * i + 6]) | ((unsigned)f2bf(v[8 * i + 7]) << 16);
    ((uint4*)p)[i] = u;
  }
}

__global__ __launch_bounds__(256) void k_zb(const float* __restrict__ x,
                                            const float* __restrict__ W2,
                                            const float* __restrict__ Ws0,
                                            const float* __restrict__ Ws1,
                                            unsigned short* __restrict__ z0T,
                                            unsigned short* __restrict__ bias0,
                                            unsigned short* __restrict__ bias1) {
  __shared__ __align__(16) float w[3][1024];
  int tid = threadIdx.x;
  for (int i = tid; i < 1024; i += 256) {
    w[0][i] = W2[i]; w[1][i] = Ws0[i]; w[2][i] = Ws1[i];
  }
  __syncthreads();
  int bx = blockIdx.x;
  int b = bx / 96, r = bx % 96, t = r >> 3, mc = r & 7;
  int m = (mc << 8) + tid;
  const float4* xp = (const float4*)(x + (((size_t)(b * 2048 + m)) * 12 + t) * 32);
  float xv[32];
#pragma unroll
  for (int i = 0; i < 8; ++i) {
    float4 v = xp[i];
    xv[4 * i + 0] = v.x; xv[4 * i + 1] = v.y; xv[4 * i + 2] = v.z; xv[4 * i + 3] = v.w;
  }
  float out[32];
  compute_mat(w[0], xv, out);
  unsigned short* zp = z0T + (size_t)b * 786432 + (size_t)(t * 32) * 2048 + m;
#pragma unroll
  for (int d = 0; d < 32; ++d) zp[(size_t)d * 2048] = f2bf(out[d]);
  size_t bb = ((size_t)(b * 2048 + m)) * 384 + t * 32;
  compute_mat(w[1], xv, out);
  store32bf(bias0 + bb, out);
  compute_mat(w[2], xv, out);
  store32bf(bias1 + bb, out);
}

// ---------------- phase C: adj @ z (+bias) MFMA GEMM ----------------
// 128x192 tile, BK=64, phase-split pipeline (T3+T4+T5): per-kk {ds_read|bar|MFMA|bar}
// + depth-2 prefetch with counted vmcnt(10); 512 blocks = 2/CU, XCD-bijective swizzle.

template <int OUT_F32>
__global__ __launch_bounds__(256, 2) void gemm_adj(const unsigned short* __restrict__ adj,
                                                   const unsigned short* __restrict__ Bt,
                                                   const unsigned short* __restrict__ bias,
                                                   void* __restrict__ outp) {
  const int tid = threadIdx.x;
  const int lane = tid & 63;
  const int wid = tid >> 6;
  const int wr = wid >> 1, wc = wid & 1;
  // XCD-bijective swizzle: 512 blocks = 8 XCDs x 64; each XCD owns 2 whole batches
  const int orig = blockIdx.x;
  const int wg = (orig & 7) * 64 + (orig >> 3);
  const int b = wg >> 5;
  const int w32 = wg & 31;
  const int m0 = ((w32 >> 1) & 15) << 7;
  const int c0 = (w32 & 1) * 192;

  // per buffer: A 128x64 (16KB) + B 192x64 (24KB) = 40KB; double = 80KB
  __shared__ __align__(16) unsigned char smem[81920];

  const unsigned short* aBase = adj + ((size_t)b << 22);
  const unsigned short* bBase = Bt + (size_t)b * 786432;
  const int jx = ((tid & 7) ^ ((tid >> 3) & 7)) << 3;
  const unsigned short* gA = aBase + (size_t)(m0 + (tid >> 3)) * 2048 + jx;
  const unsigned short* gB = bBase + (size_t)(c0 + (tid >> 3)) * 2048 + jx;

  int aoff[2][4], boff[2][6];
#pragma unroll
  for (int kk = 0; kk < 2; ++kk) {
    int c = kk * 4 + (lane >> 4);
#pragma unroll
    for (int f = 0; f < 4; ++f) {
      int rA = wr * 64 + f * 16 + (lane & 15);
      aoff[kk][f] = rA * 128 + ((c ^ (rA & 7)) << 4);
    }
#pragma unroll
    for (int n = 0; n < 6; ++n) {
      int rB = wc * 96 + n * 16 + (lane & 15);
      boff[kk][n] = 16384 + rB * 128 + ((c ^ (rB & 7)) << 4);
    }
  }

  f32x4 acc[4][6] = {};

#define STAGE(BUF, KT)                                                              \
  {                                                                                 \
    _Pragma("unroll") for (int ii = 0; ii < 4; ++ii)                                \
        gload16(gA + (size_t)ii * 65536 + (KT)*64, smem + (BUF) + ii * 4096 + tid * 16); \
    _Pragma("unroll") for (int ii = 0; ii < 6; ++ii)                                \
        gload16(gB + (size_t)ii * 65536 + (KT)*64,                                  \
                smem + (BUF) + 16384 + ii * 4096 + tid * 16);                       \
  }

  // prologue: tiles 0 and 1 in flight; wait for tile 0 only
  STAGE(0, 0);
  STAGE(40960, 1);
  asm volatile("s_waitcnt vmcnt(10)" ::: "memory");
  __builtin_amdgcn_s_barrier();

  int cur = 0;
  for (int kt = 0; kt < 32; ++kt) {
#pragma unroll
    for (int kk = 0; kk < 2; ++kk) {
      // phase: ds_read this kk's fragments
      bf16x8 af[4], bfv[6];
#pragma unroll
      for (int f = 0; f < 4; ++f) af[f] = *(const bf16x8*)(smem + cur + aoff[kk][f]);
#pragma unroll
      for (int n = 0; n < 6; ++n) bfv[n] = *(const bf16x8*)(smem + cur + boff[kk][n]);
      __builtin_amdgcn_s_barrier();
      __builtin_amdgcn_s_setprio(1);
#pragma unroll
      for (int m = 0; m < 4; ++m)
#pragma unroll
        for (int n = 0; n < 6; ++n)
          acc[m][n] = __builtin_amdgcn_mfma_f32_16x16x32_bf16(af[m], bfv[n], acc[m][n], 0, 0, 0);
      __builtin_amdgcn_s_setprio(0);
      __builtin_amdgcn_s_barrier();  // all waves done reading cur's kk data
    }
    // tile boundary: buf[cur] fully consumed -> refill with kt+2, counted wait for kt+1
    if (kt < 30) {
      STAGE(cur, kt + 2);
      asm volatile("s_waitcnt vmcnt(10)" ::: "memory");  // kt+1 landed; kt+2 in flight
      __builtin_amdgcn_s_barrier();
    } else if (kt == 30) {
      asm volatile("s_waitcnt vmcnt(0)" ::: "memory");   // drain kt=31's loads
      __builtin_amdgcn_s_barrier();
    }
    cur ^= 40960;
  }
#undef STAGE

  const int cl = lane & 15;
  const int r4 = (lane >> 4) << 2;
  const unsigned short* bi = bias + (size_t)b * 786432;
  if (OUT_F32) {
    float* o = (float*)outp + (size_t)b * 786432;
#pragma unroll
    for (int m = 0; m < 4; ++m) {
      int row0 = m0 + wr * 64 + m * 16 + r4;
#pragma unroll
      for (int n = 0; n < 6; ++n) {
        int col = c0 + wc * 96 + n * 16 + cl;
#pragma unroll
        for (int r = 0; r < 4; ++r) {
          int row = row0 + r;
          o[(size_t)row * 384 + col] = acc[m][n][r] + bf2f(bi[(size_t)row * 384 + col]);
        }
      }
    }
  } else {
    unsigned short* o = (unsigned short*)outp + (size_t)b * 786432;
#pragma unroll
    for (int m = 0; m < 4; ++m) {
      int row0 = m0 + wr * 64 + m * 16 + r4;
#pragma unroll
      for (int n = 0; n < 6; ++n) {
        int col = c0 + wc * 96 + n * 16 + cl;
        ushort4 pk;
        pk.x = f2bf(acc[m][n][0] + bf2f(bi[(size_t)(row0 + 0) * 384 + col]));
        pk.y = f2bf(acc[m][n][1] + bf2f(bi[(size_t)(row0 + 1) * 384 + col]));
        pk.z = f2bf(acc[m][n][2] + bf2f(bi[(size_t)(row0 + 2) * 384 + col]));
        pk.w = f2bf(acc[m][n][3] + bf2f(bi[(size_t)(row0 + 3) * 384 + col]));
        *(ushort4*)(o + (size_t)col * 2048 + row0) = pk;
      }
    }
  }
}

// ---------------- launch ----------------

extern "C" void kernel_launch(void* const* d_in, const int* in_sizes, int n_in,
                              void* d_out, int out_size, void* d_ws, size_t ws_size,
                              hipStream_t stream) {
  const float* x = (const float*)d_in[0];
  const float* dis = (const float*)d_in[1];
  const float* K_S = (const float*)d_in[2];
  const float* V_S = (const float*)d_in[3];
  const float* K_T = (const float*)d_in[4];
  const float* V_T = (const float*)d_in[5];
  const float* W_Q0 = (const float*)d_in[6];
  const float* W_QS = (const float*)d_in[7];
  const float* W_QT = (const float*)d_in[8];
  const float* W2 = (const float*)d_in[9];
  const float* W_s0 = (const float*)d_in[10];
  const float* W_s1 = (const float*)d_in[11];

  char* ws = (char*)d_ws;
  float* xmn = (float*)(ws + 0);                             //     24,576 B
  float* pqs = (float*)(ws + 28672);                         //  2,097,152 B
  unsigned short* ets_bf = (unsigned short*)(ws + 2130432);  //  1,048,576 B
  unsigned short* adj = (unsigned short*)(ws + 3179008);     // 134,217,728 B
  unsigned short* z0T = (unsigned short*)(ws + 137396736);   // 25,165,824 B
  unsigned short* z1T = (unsigned short*)(ws + 162562560);   // 25,165,824 B
  unsigned short* bias0 = (unsigned short*)(ws + 187728384); // 25,165,824 B
  unsigned short* bias1 = (unsigned short*)(ws + 212894208); // 25,165,824 B

  k_xmn<<<192, 256, 0, stream>>>(x, xmn);
  k_qs<<<512, 256, 0, stream>>>(x, W_Q0, W_QS, pqs);
  k_post<<<16, 256, 0, stream>>>(pqs, xmn, W_Q0, W_QT, K_T, K_S, V_T, V_S, ets_bf);
  k_adj<<<2048, 512, 0, stream>>>(ets_bf, dis, adj);
  k_zb<<<1536, 256, 0, stream>>>(x, W2, W_s0, W_s1, z0T, bias0, bias1);
  gemm_adj<0><<<512, 256, 0, stream>>>(adj, z0T, bias0, (void*)z1T);
  gemm_adj<1><<<512, 256, 0, stream>>>(adj, z1T, bias1, d_out);
}

// Round 9
// 335.629 us; speedup vs baseline: 1.5347x; 1.2057x over previous
//
#include <hip/hip_runtime.h>

typedef __bf16 bf16x8 __attribute__((ext_vector_type(8)));
typedef float f32x4 __attribute__((ext_vector_type(4)));

__device__ __forceinline__ unsigned short f2bf(float f) {
  unsigned u = __builtin_bit_cast(unsigned, f);
  u += 0x7fffu + ((u >> 16) & 1u);
  return (unsigned short)(u >> 16);
}
__device__ __forceinline__ float bf2f(unsigned short h) {
  unsigned u = ((unsigned)h) << 16;
  return __builtin_bit_cast(float, u);
}
__device__ __forceinline__ unsigned char f2fp8(float v) {
  return (unsigned char)(__builtin_amdgcn_cvt_pk_fp8_f32(v, v, 0, false) & 0xff);
}
__device__ __forceinline__ void gload16(const void* g, void* l) {
  __builtin_amdgcn_global_load_lds((const __attribute__((address_space(1))) void*)g,
                                   (__attribute__((address_space(3))) void*)l, 16, 0, 0);
}
// byte permutation within a 128-byte K-panel row: k = kk*32+g*8+e -> byte g*32+kk*8+e
__device__ __forceinline__ int perm7(int x) {
  return ((x >> 3) & 3) * 32 + ((x >> 5) << 3) + (x & 7);
}

// ---------------- phase A ----------------

// xmn[b,t,k] = mean_n x[b,:,t,k]
__global__ __launch_bounds__(256) void k_xmn(const float* __restrict__ x, float* __restrict__ xmn) {
  int b = blockIdx.x / 12, t = blockIdx.x % 12;
  int k = threadIdx.x & 31, sl = threadIdx.x >> 5;
  const float* xp = x + (size_t)b * 786432 + (size_t)t * 32 + k;
  float s = 0.f;
  for (int i = 0; i < 256; ++i) {
    int n = (sl << 8) + i;
    s += xp[(size_t)n * 384];
  }
  __shared__ float red[8][32];
  red[sl][k] = s;
  __syncthreads();
  if (threadIdx.x < 32) {
    float tot = 0.f;
#pragma unroll
    for (int j = 0; j < 8; ++j) tot += red[j][threadIdx.x];
    xmn[(b * 12 + t) * 32 + threadIdx.x] = tot * (1.0f / 2048.0f);
  }
}

// Fused: per block (4 n-values): mean_t(x) -> @W_Q0 -> contract with W_QS rows
__global__ __launch_bounds__(256) void k_qs(const float* __restrict__ x,
                                            const float* __restrict__ W_Q0,
                                            const float* __restrict__ W_QS,
                                            float* __restrict__ pqs) {
  __shared__ __align__(16) float w0[1024];
  __shared__ float lm[2048];
  __shared__ float lq[2048];
  __shared__ float red[4][16][64];
  int tid = threadIdx.x;
#pragma unroll
  for (int i = 0; i < 4; ++i) w0[tid + i * 256] = W_Q0[tid + i * 256];
  int n0 = blockIdx.x * 4;
#pragma unroll
  for (int j = 0; j < 8; ++j) {
    int i = tid + j * 256;
    int b = i >> 7, r = i & 127;
    int n = n0 + (r >> 5), k = r & 31;
    const float* xp = x + ((size_t)(b * 2048 + n) * 12) * 32 + k;
    float s = 0.f;
#pragma unroll
    for (int t = 0; t < 12; ++t) s += xp[t * 32];
    lm[i] = s * (1.0f / 12.0f);
  }
  __syncthreads();
#pragma unroll
  for (int j = 0; j < 8; ++j) {
    int i = tid + j * 256;
    int br = i >> 5, q = i & 31;
    const float* mrow = &lm[br * 32];
    float a = 0.f;
#pragma unroll
    for (int k = 0; k < 32; ++k) a += mrow[k] * w0[k * 32 + q];
    lq[i] = a;
  }
  __syncthreads();
  int lane = tid & 63, wid = tid >> 6;
  float acc[16];
#pragma unroll
  for (int b = 0; b < 16; ++b) acc[b] = 0.f;
  for (int rl = 0; rl < 32; ++rl) {
    int r = wid * 32 + rl;
    float wv = W_QS[(size_t)(n0 * 32 + r) * 64 + lane];
#pragma unroll
    for (int b = 0; b < 16; ++b) acc[b] += lq[b * 128 + r] * wv;
  }
#pragma unroll
  for (int b = 0; b < 16; ++b) red[wid][b][lane] = acc[b];
  __syncthreads();
#pragma unroll
  for (int it = 0; it < 4; ++it) {
    int idx = tid + it * 256;
    float s = red[0][idx >> 6][idx & 63] + red[1][idx >> 6][idx & 63] +
              red[2][idx >> 6][idx & 63] + red[3][idx >> 6][idx & 63];
    pqs[(size_t)blockIdx.x * 1024 + idx] = s;
  }
}

// Fused tail: qs-reduce + qt + attn + ets  (one block per batch b)
__global__ __launch_bounds__(256) void k_post(const float* __restrict__ pqs,
                                              const float* __restrict__ xmn,
                                              const float* __restrict__ W_Q0,
                                              const float* __restrict__ W_QT,
                                              const float* __restrict__ K_T,
                                              const float* __restrict__ K_S,
                                              const float* __restrict__ V_T,
                                              const float* __restrict__ V_S,
                                              unsigned short* __restrict__ ets_bf) {
  const int b = blockIdx.x, tid = threadIdx.x;
  __shared__ float red[4][64];
  __shared__ float qs_s[64];
  __shared__ float qt_s[64];
  __shared__ float xp[384];
  __shared__ float at_s[8];

  {
    float s = 0.f;
    for (int c = tid >> 6; c < 512; c += 4) s += pqs[(size_t)c * 1024 + b * 64 + (tid & 63)];
    red[tid >> 6][tid & 63] = s;
  }
  for (int i = tid; i < 384; i += 256) {
    int t = i >> 5, q = i & 31;
    float a = 0.f;
#pragma unroll
    for (int k = 0; k < 32; ++k) a += xmn[(b * 12 + t) * 32 + k] * W_Q0[k * 32 + q];
    xp[i] = a;
  }
  __syncthreads();
  if (tid < 64) qs_s[tid] = red[0][tid] + red[1][tid] + red[2][tid] + red[3][tid];
  __syncthreads();
  if (tid < 64) {
    float q = 0.f;
    for (int i = 0; i < 384; ++i) q += xp[i] * W_QT[i * 64 + tid];
    qt_s[tid] = q;
  }
  __syncthreads();
  if (tid < 64) {
    int lane = tid;
    float qsv = qs_s[lane], qtv = qt_s[lane];
    float lt[4], ls[4];
#pragma unroll
    for (int h = 0; h < 4; ++h) {
      float p = qtv * K_T[h * 64 + lane];
#pragma unroll
      for (int off = 32; off > 0; off >>= 1) p += __shfl_xor(p, off);
      lt[h] = p;
      float p2 = qsv * K_S[h * 64 + lane];
#pragma unroll
      for (int off = 32; off > 0; off >>= 1) p2 += __shfl_xor(p2, off);
      ls[h] = p2;
    }
    if (lane == 0) {
      const float scale = 0.125f;
      float mt = fmaxf(fmaxf(lt[0], lt[1]), fmaxf(lt[2], lt[3]));
      float ms = fmaxf(fmaxf(ls[0], ls[1]), fmaxf(ls[2], ls[3]));
      float et[4], es[4], st = 0.f, ss = 0.f;
#pragma unroll
      for (int h = 0; h < 4; ++h) {
        et[h] = __expf((lt[h] - mt) * scale); st += et[h];
        es[h] = __expf((ls[h] - ms) * scale); ss += es[h];
      }
#pragma unroll
      for (int h = 0; h < 4; ++h) {
        at_s[h] = et[h] / st;
        at_s[4 + h] = es[h] / ss;
      }
    }
  }
  __syncthreads();
  float a0 = at_s[0], a1 = at_s[1], a2 = at_s[2], a3 = at_s[3];
  float s0 = at_s[4], s1 = at_s[5], s2 = at_s[6], s3 = at_s[7];
  for (int n = tid; n < 2048; n += 256) {
    float v[10];
#pragma unroll
    for (int c = 0; c < 10; ++c) {
      int o = n * 10 + c;
      v[c] = a0 * V_T[o] + a1 * V_T[20480 + o] + a2 * V_T[40960 + o] + a3 * V_T[61440 + o] +
             s0 * V_S[o] + s1 * V_S[20480 + o] + s2 * V_S[40960 + o] + s3 * V_S[61440 + o];
    }
    uint4 lo, hi;
    lo.x = (unsigned)f2bf(v[0]) | ((unsigned)f2bf(v[1]) << 16);
    lo.y = (unsigned)f2bf(v[2]) | ((unsigned)f2bf(v[3]) << 16);
    lo.z = (unsigned)f2bf(v[4]) | ((unsigned)f2bf(v[5]) << 16);
    lo.w = (unsigned)f2bf(v[6]) | ((unsigned)f2bf(v[7]) << 16);
    hi.x = (unsigned)f2bf(v[8]) | ((unsigned)f2bf(v[9]) << 16);
    hi.y = 0; hi.z = 0; hi.w = 0;
    size_t idx = (size_t)b * 2048 + n;
    *(uint4*)(ets_bf + idx * 16) = lo;
    *(uint4*)(ets_bf + idx * 16 + 8) = hi;
  }
}

// ---------------- phase B: MFMA adjacency + row softmax -> fp8 (x256, k-permuted) -----

__global__ __launch_bounds__(512, 4) void k_adj(const unsigned short* __restrict__ ets_bf,
                                                const float* __restrict__ dis,
                                                unsigned char* __restrict__ adjf) {
  __shared__ __align__(16) unsigned char Bsh[65536];
  __shared__ float st_max[8][16];
  __shared__ float st_sum[8][16];
  __shared__ float rowmax_s[16];
  __shared__ float rowinv_s[16];

  const int tid = threadIdx.x;
  const int lane = tid & 63;
  const int w = tid >> 6;
  const int cl = lane & 15;
  const int g = lane >> 4;
  const int b = blockIdx.x >> 7;
  const int n0 = (blockIdx.x & 127) << 4;

  const unsigned char* gsrc = (const unsigned char*)(ets_bf + (size_t)b * 32768);
#pragma unroll
  for (int it = 0; it < 8; ++it)
    gload16(gsrc + it * 8192 + tid * 16, Bsh + it * 8192 + (w << 10));
  __syncthreads();

  uint4 araw = *(const uint4*)(ets_bf + ((size_t)b * 2048 + n0 + cl) * 16 + (g & 1) * 8);
  if (g >= 2) { araw.x = 0; araw.y = 0; araw.z = 0; araw.w = 0; }
  bf16x8 afrag = __builtin_bit_cast(bf16x8, araw);

  f32x4 acc[16];
  const int cbase = (w << 8) + cl;
#pragma unroll
  for (int n = 0; n < 16; ++n) {
    uint4 braw = *(const uint4*)(Bsh + (size_t)(cbase + n * 16) * 32 + (g & 1) * 16);
    if (g >= 2) { braw.x = 0; braw.y = 0; braw.z = 0; braw.w = 0; }
    bf16x8 bfrag = __builtin_bit_cast(bf16x8, braw);
    acc[n] = __builtin_amdgcn_mfma_f32_16x16x32_bf16(afrag, bfrag, (f32x4){0.f, 0.f, 0.f, 0.f},
                                                     0, 0, 0);
  }

  float mx[4] = {-1e30f, -1e30f, -1e30f, -1e30f};
  const float* dbase = dis + (size_t)(n0 + g * 4) * 2048 + (w << 8) + cl;
#pragma unroll
  for (int n = 0; n < 16; ++n) {
#pragma unroll
    for (int j = 0; j < 4; ++j) {
      float s = fmaxf(acc[n][j] + dbase[(size_t)j * 2048 + n * 16], 0.f);
      acc[n][j] = s;
      mx[j] = fmaxf(mx[j], s);
    }
  }
#pragma unroll
  for (int j = 0; j < 4; ++j) {
    mx[j] = fmaxf(mx[j], __shfl_xor(mx[j], 1));
    mx[j] = fmaxf(mx[j], __shfl_xor(mx[j], 2));
    mx[j] = fmaxf(mx[j], __shfl_xor(mx[j], 4));
    mx[j] = fmaxf(mx[j], __shfl_xor(mx[j], 8));
  }
  if (cl == 0) {
#pragma unroll
    for (int j = 0; j < 4; ++j) st_max[w][g * 4 + j] = mx[j];
  }
  __syncthreads();
  if (tid < 16) {
    float m = st_max[0][tid];
#pragma unroll
    for (int ww = 1; ww < 8; ++ww) m = fmaxf(m, st_max[ww][tid]);
    rowmax_s[tid] = m;
  }
  __syncthreads();

  float rm[4], sm[4] = {0.f, 0.f, 0.f, 0.f};
#pragma unroll
  for (int j = 0; j < 4; ++j) rm[j] = rowmax_s[g * 4 + j];
#pragma unroll
  for (int n = 0; n < 16; ++n) {
#pragma unroll
    for (int j = 0; j < 4; ++j) {
      float e = __expf(acc[n][j] - rm[j]);
      acc[n][j] = e;
      sm[j] += e;
    }
  }
#pragma unroll
  for (int j = 0; j < 4; ++j) {
    sm[j] += __shfl_xor(sm[j], 1);
    sm[j] += __shfl_xor(sm[j], 2);
    sm[j] += __shfl_xor(sm[j], 4);
    sm[j] += __shfl_xor(sm[j], 8);
  }
  if (cl == 0) {
#pragma unroll
    for (int j = 0; j < 4; ++j) st_sum[w][g * 4 + j] = sm[j];
  }
  __syncthreads();
  if (tid < 16) {
    float s = st_sum[0][tid];
#pragma unroll
    for (int ww = 1; ww < 8; ++ww) s += st_sum[ww][tid];
    rowinv_s[tid] = 256.0f / s;  // x256 so fp8 stays in normal range
  }
  __syncthreads();  // all Bsh B-reads done -> safe to reuse as transpose buf

  // normalize + fp8 + k-permute into per-wave transpose buffer [16 rows][256 bytes]
  unsigned char* Tw = Bsh + (w << 12);
  float inv[4];
#pragma unroll
  for (int j = 0; j < 4; ++j) inv[j] = rowinv_s[g * 4 + j];
#pragma unroll
  for (int n = 0; n < 16; ++n) {
    int ml = n * 16 + cl;
    int pb = ((ml >> 7) << 7) + perm7(ml & 127);
#pragma unroll
    for (int j = 0; j < 4; ++j)
      Tw[(g * 4 + j) * 256 + pb] = f2fp8(acc[n][j] * inv[j]);
  }
  __syncthreads();

  unsigned char* obase = adjf + ((size_t)b * 2048 + n0) * 2048 + (w << 8);
#pragma unroll
  for (int r = 0; r < 16; ++r) {
    unsigned v = *(const unsigned*)(Tw + r * 256 + lane * 4);
    *(unsigned*)(obase + (size_t)r * 2048 + lane * 4) = v;
  }
}

// ---------------- phase C producers ----------------

__device__ __forceinline__ void compute_mat(const float* w, const float* xv, float* out) {
  float4 a[8];
#pragma unroll
  for (int i = 0; i < 8; ++i) a[i] = make_float4(0.f, 0.f, 0.f, 0.f);
#pragma unroll
  for (int k = 0; k < 32; ++k) {
    float xk = xv[k];
#pragma unroll
    for (int d4 = 0; d4 < 8; ++d4) {
      float4 wv = ((const float4*)(w + k * 32))[d4];
      a[d4].x += xk * wv.x; a[d4].y += xk * wv.y; a[d4].z += xk * wv.z; a[d4].w += xk * wv.w;
    }
  }
#pragma unroll
  for (int d4 = 0; d4 < 8; ++d4) {
    out[4 * d4 + 0] = a[d4].x; out[4 * d4 + 1] = a[d4].y;
    out[4 * d4 + 2] = a[d4].z; out[4 * d4 + 3] = a[d4].w;
  }
}

__device__ __forceinline__ void store32bf(unsigned short* p, const float* v) {
#pragma unroll
  for (int i = 0; i < 4; ++i) {
    uint4 u;
    u.x = (unsigned)f2bf(v[8 * i + 0]) | ((unsigned)f2bf(v[8 * i + 1]) << 16);
    u.y = (unsigned)f2bf(v[8 * i + 2]) | ((unsigned)f2bf(v[8 * i + 3]) << 16);
    u.z = (unsigned)f2bf(v[8 * i + 4]) | ((unsigned)f2bf(v[8 * i + 5]) << 16);
    u.w = (unsigned)f2bf(v[8 * i + 6]) | ((unsigned)f2bf(v[8 * i + 7]) << 16);
    ((uint4*)p)[i] = u;
  }
}

__global__ __launch_bounds__(256) void k_zb(const float* __restrict__ x,
                                            const float* __restrict__ W2,
                                            const float* __restrict__ Ws0,
                                            const float* __restrict__ Ws1,
                                            unsigned char* __restrict__ z0Tf,
                                            unsigned short* __restrict__ bias0,
                                            unsigned short* __restrict__ bias1) {
  __shared__ __align__(16) float w[3][1024];
  int tid = threadIdx.x;
  for (int i = tid; i < 1024; i += 256) {
    w[0][i] = W2[i]; w[1][i] = Ws0[i]; w[2][i] = Ws1[i];
  }
  __syncthreads();
  int bx = blockIdx.x;
  int b = bx / 96, r = bx % 96, t = r >> 3, mc = r & 7;
  int m = (mc << 8) + tid;
  const float4* xp = (const float4*)(x + (((size_t)(b * 2048 + m)) * 12 + t) * 32);
  float xv[32];
#pragma unroll
  for (int i = 0; i < 8; ++i) {
    float4 v = xp[i];
    xv[4 * i + 0] = v.x; xv[4 * i + 1] = v.y; xv[4 * i + 2] = v.z; xv[4 * i + 3] = v.w;
  }
  float out[32];
  compute_mat(w[0], xv, out);
  unsigned char* zp = z0Tf + (size_t)b * 786432;
  const int cb = ((m >> 7) << 7) + perm7(m & 127);
#pragma unroll
  for (int d = 0; d < 32; ++d) zp[(size_t)(t * 32 + d) * 2048 + cb] = f2fp8(out[d]);
  size_t bb = ((size_t)(b * 2048 + m)) * 384 + t * 32;
  compute_mat(w[1], xv, out);
  store32bf(bias0 + bb, out);
  compute_mat(w[2], xv, out);
  store32bf(bias1 + bb, out);
}

// ---------------- phase C: (adj*256) @ z fp8 MFMA GEMM ----------------
// 128x192 tile, BK=128 (fp8, k-permuted layout), counted-vmcnt double buffer,
// 512 blocks = 2/CU, XCD-bijective swizzle. Epilogue divides by 256, adds bf16 bias.

template <int OUT_F32>
__global__ __launch_bounds__(256, 2) void gemm_adj(const unsigned char* __restrict__ adjf,
                                                   const unsigned char* __restrict__ Bt,
                                                   const unsigned short* __restrict__ bias,
                                                   void* __restrict__ outp) {
  const int tid = threadIdx.x;
  const int lane = tid & 63;
  const int wid = tid >> 6;
  const int wr = wid >> 1, wc = wid & 1;
  const int orig = blockIdx.x;
  const int wg = (orig & 7) * 64 + (orig >> 3);
  const int b = wg >> 5;
  const int w32 = wg & 31;
  const int m0 = ((w32 >> 1) & 15) << 7;
  const int c0 = (w32 & 1) * 192;

  // per buffer: A 128x128B (16KB) + B 192x128B (24KB) = 40KB; double = 80KB
  __shared__ __align__(16) unsigned char smem[81920];

  const unsigned char* aBase = adjf + ((size_t)b << 22);
  const unsigned char* bBase = Bt + (size_t)b * 786432;
  const int jx = ((tid & 7) ^ ((tid >> 3) & 7)) << 4;  // inverse-swizzled 16B chunk (bytes)
  const unsigned char* gA = aBase + (size_t)(m0 + (tid >> 3)) * 2048 + jx;
  const unsigned char* gB = bBase + (size_t)(c0 + (tid >> 3)) * 2048 + jx;

  int aoff[2][4], boff[2][6];
#pragma unroll
  for (int kkp = 0; kkp < 2; ++kkp) {
    int c = ((lane >> 4) << 1) + kkp;  // logical 16B chunk: covers kk=2kkp,2kkp+1 for group g
#pragma unroll
    for (int f = 0; f < 4; ++f) {
      int rA = wr * 64 + f * 16 + (lane & 15);
      aoff[kkp][f] = rA * 128 + ((c ^ (rA & 7)) << 4);
    }
#pragma unroll
    for (int n = 0; n < 6; ++n) {
      int rB = wc * 96 + n * 16 + (lane & 15);
      boff[kkp][n] = 16384 + rB * 128 + ((c ^ (rB & 7)) << 4);
    }
  }

  f32x4 acc[4][6] = {};

#define STAGE(BUF, KT)                                                               \
  {                                                                                  \
    _Pragma("unroll") for (int ii = 0; ii < 4; ++ii)                                 \
        gload16(gA + (size_t)ii * 65536 + (KT)*128, smem + (BUF) + ii * 4096 + tid * 16); \
    _Pragma("unroll") for (int ii = 0; ii < 6; ++ii)                                 \
        gload16(gB + (size_t)ii * 65536 + (KT)*128,                                  \
                smem + (BUF) + 16384 + ii * 4096 + tid * 16);                        \
  }

  STAGE(0, 0);

  int cur = 0;
  for (int kt = 0; kt < 16; ++kt) {
    const int nxt = cur ^ 40960;
    if (kt < 15) {
      STAGE(nxt, kt + 1);
      asm volatile("s_waitcnt vmcnt(10)" ::: "memory");  // cur's 10 landed; nxt's in flight
    } else {
      asm volatile("s_waitcnt vmcnt(0)" ::: "memory");
    }
    __builtin_amdgcn_s_barrier();
#pragma unroll
    for (int kkp = 0; kkp < 2; ++kkp) {
      ulong2 av[4], bv[6];
#pragma unroll
      for (int f = 0; f < 4; ++f) av[f] = *(const ulong2*)(smem + cur + aoff[kkp][f]);
#pragma unroll
      for (int n = 0; n < 6; ++n) bv[n] = *(const ulong2*)(smem + cur + boff[kkp][n]);
#pragma unroll
      for (int m = 0; m < 4; ++m)
#pragma unroll
        for (int n = 0; n < 6; ++n)
          acc[m][n] = __builtin_amdgcn_mfma_f32_16x16x32_fp8_fp8(
              (long)av[m].x, (long)bv[n].x, acc[m][n], 0, 0, 0);
#pragma unroll
      for (int m = 0; m < 4; ++m)
#pragma unroll
        for (int n = 0; n < 6; ++n)
          acc[m][n] = __builtin_amdgcn_mfma_f32_16x16x32_fp8_fp8(
              (long)av[m].y, (long)bv[n].y, acc[m][n], 0, 0, 0);
    }
    __builtin_amdgcn_s_barrier();  // all waves done reading cur before next STAGE overwrites
    cur = nxt;
  }
#undef STAGE

  const float inv256 = 0.00390625f;
  const int cl = lane & 15;
  const int r4 = (lane >> 4) << 2;
  const unsigned short* bi = bias + (size_t)b * 786432;
  if (OUT_F32) {
    float* o = (float*)outp + (size_t)b * 786432;
#pragma unroll
    for (int m = 0; m < 4; ++m) {
      int row0 = m0 + wr * 64 + m * 16 + r4;
#pragma unroll
      for (int n = 0; n < 6; ++n) {
        int col = c0 + wc * 96 + n * 16 + cl;
#pragma unroll
        for (int r = 0; r < 4; ++r) {
          int row = row0 + r;
          o[(size_t)row * 384 + col] = acc[m][n][r] * inv256 + bf2f(bi[(size_t)row * 384 + col]);
        }
      }
    }
  } else {
    unsigned char* o = (unsigned char*)outp + (size_t)b * 786432;
#pragma unroll
    for (int m = 0; m < 4; ++m) {
      int row0 = m0 + wr * 64 + m * 16 + r4;
      const int pb = ((row0 >> 7) << 7) + perm7(row0 & 127);  // 4 consecutive bytes for r=0..3
#pragma unroll
      for (int n = 0; n < 6; ++n) {
        int col = c0 + wc * 96 + n * 16 + cl;
        float v0 = acc[m][n][0] * inv256 + bf2f(bi[(size_t)(row0 + 0) * 384 + col]);
        float v1 = acc[m][n][1] * inv256 + bf2f(bi[(size_t)(row0 + 1) * 384 + col]);
        float v2 = acc[m][n][2] * inv256 + bf2f(bi[(size_t)(row0 + 2) * 384 + col]);
        float v3 = acc[m][n][3] * inv256 + bf2f(bi[(size_t)(row0 + 3) * 384 + col]);
        unsigned u = __builtin_amdgcn_cvt_pk_fp8_f32(v0, v1, 0, false);
        u = __builtin_amdgcn_cvt_pk_fp8_f32(v2, v3, (int)u, true);
        *(unsigned*)(o + (size_t)col * 2048 + pb) = u;
      }
    }
  }
}

// ---------------- launch ----------------

extern "C" void kernel_launch(void* const* d_in, const int* in_sizes, int n_in,
                              void* d_out, int out_size, void* d_ws, size_t ws_size,
                              hipStream_t stream) {
  const float* x = (const float*)d_in[0];
  const float* dis = (const float*)d_in[1];
  const float* K_S = (const float*)d_in[2];
  const float* V_S = (const float*)d_in[3];
  const float* K_T = (const float*)d_in[4];
  const float* V_T = (const float*)d_in[5];
  const float* W_Q0 = (const float*)d_in[6];
  const float* W_QS = (const float*)d_in[7];
  const float* W_QT = (const float*)d_in[8];
  const float* W2 = (const float*)d_in[9];
  const float* W_s0 = (const float*)d_in[10];
  const float* W_s1 = (const float*)d_in[11];

  char* ws = (char*)d_ws;
  float* xmn = (float*)(ws + 0);                             //     24,576 B
  float* pqs = (float*)(ws + 28672);                         //  2,097,152 B
  unsigned short* ets_bf = (unsigned short*)(ws + 2130432);  //  1,048,576 B
  unsigned char* adjf = (unsigned char*)(ws + 3179008);      // 67,108,864 B
  unsigned char* z0Tf = (unsigned char*)(ws + 70287872);     // 12,582,912 B
  unsigned char* z1Tf = (unsigned char*)(ws + 82870784);     // 12,582,912 B
  unsigned short* bias0 = (unsigned short*)(ws + 95453696);  // 25,165,824 B
  unsigned short* bias1 = (unsigned short*)(ws + 120619520); // 25,165,824 B

  k_xmn<<<192, 256, 0, stream>>>(x, xmn);
  k_qs<<<512, 256, 0, stream>>>(x, W_Q0, W_QS, pqs);
  k_post<<<16, 256, 0, stream>>>(pqs, xmn, W_Q0, W_QT, K_T, K_S, V_T, V_S, ets_bf);
  k_adj<<<2048, 512, 0, stream>>>(ets_bf, dis, adjf);
  k_zb<<<1536, 256, 0, stream>>>(x, W2, W_s0, W_s1, z0Tf, bias0, bias1);
  gemm_adj<0><<<512, 256, 0, stream>>>(adjf, z0Tf, bias0, (void*)z1Tf);
  gemm_adj<1><<<512, 256, 0, stream>>>(adjf, z1Tf, bias1, d_out);
}

// Round 10
// 290.019 us; speedup vs baseline: 1.7760x; 1.1573x over previous
//
#include <hip/hip_runtime.h>

typedef __bf16 bf16x8 __attribute__((ext_vector_type(8)));
typedef float f32x4 __attribute__((ext_vector_type(4)));

__device__ __forceinline__ unsigned short f2bf(float f) {
  unsigned u = __builtin_bit_cast(unsigned, f);
  u += 0x7fffu + ((u >> 16) & 1u);
  return (unsigned short)(u >> 16);
}
__device__ __forceinline__ float bf2f(unsigned short h) {
  unsigned u = ((unsigned)h) << 16;
  return __builtin_bit_cast(float, u);
}
__device__ __forceinline__ unsigned char f2fp8(float v) {
  return (unsigned char)(__builtin_amdgcn_cvt_pk_fp8_f32(v, v, 0, false) & 0xff);
}
__device__ __forceinline__ void gload16(const void* g, void* l) {
  __builtin_amdgcn_global_load_lds((const __attribute__((address_space(1))) void*)g,
                                   (__attribute__((address_space(3))) void*)l, 16, 0, 0);
}
// byte permutation within a 128-byte K-panel row: k = kk*32+g*8+e -> byte g*32+kk*8+e
__device__ __forceinline__ int perm7(int x) {
  return ((x >> 3) & 3) * 32 + ((x >> 5) << 3) + (x & 7);
}

// ---------------- phase A ----------------

// pxmn[c,b,t,k] = sum over n-chunk c of x[b,:,t,k]   (768 blocks = 3/CU)
__global__ __launch_bounds__(256) void k_xmn(const float* __restrict__ x,
                                             float* __restrict__ pxmn) {
  int bx = blockIdx.x;
  int b = bx / 48, r = bx % 48, t = r >> 2, c = r & 3;
  int k = threadIdx.x & 31, sl = threadIdx.x >> 5;
  const float* xp = x + (size_t)b * 786432 + (size_t)(c * 512) * 384 + (size_t)t * 32 + k;
  float s = 0.f;
  for (int i = 0; i < 64; ++i) s += xp[(size_t)((sl << 6) + i) * 384];
  __shared__ float red[8][32];
  red[sl][k] = s;
  __syncthreads();
  if (threadIdx.x < 32) {
    float tot = 0.f;
#pragma unroll
    for (int j = 0; j < 8; ++j) tot += red[j][threadIdx.x];
    pxmn[((c * 16 + b) * 12 + t) * 32 + threadIdx.x] = tot;
  }
}

// Fused: per block (4 n-values): mean_t(x) -> @W_Q0 -> contract with W_QS rows
__global__ __launch_bounds__(256) void k_qs(const float* __restrict__ x,
                                            const float* __restrict__ W_Q0,
                                            const float* __restrict__ W_QS,
                                            float* __restrict__ pqs) {
  __shared__ __align__(16) float w0[1024];
  __shared__ float lm[2048];
  __shared__ float lq[2048];
  __shared__ float red[4][16][64];
  int tid = threadIdx.x;
#pragma unroll
  for (int i = 0; i < 4; ++i) w0[tid + i * 256] = W_Q0[tid + i * 256];
  int n0 = blockIdx.x * 4;
#pragma unroll
  for (int j = 0; j < 8; ++j) {
    int i = tid + j * 256;
    int b = i >> 7, r = i & 127;
    int n = n0 + (r >> 5), k = r & 31;
    const float* xp = x + ((size_t)(b * 2048 + n) * 12) * 32 + k;
    float s = 0.f;
#pragma unroll
    for (int t = 0; t < 12; ++t) s += xp[t * 32];
    lm[i] = s * (1.0f / 12.0f);
  }
  __syncthreads();
#pragma unroll
  for (int j = 0; j < 8; ++j) {
    int i = tid + j * 256;
    int br = i >> 5, q = i & 31;
    const float* mrow = &lm[br * 32];
    float a = 0.f;
#pragma unroll
    for (int k = 0; k < 32; ++k) a += mrow[k] * w0[k * 32 + q];
    lq[i] = a;
  }
  __syncthreads();
  int lane = tid & 63, wid = tid >> 6;
  float acc[16];
#pragma unroll
  for (int b = 0; b < 16; ++b) acc[b] = 0.f;
  for (int rl = 0; rl < 32; ++rl) {
    int r = wid * 32 + rl;
    float wv = W_QS[(size_t)(n0 * 32 + r) * 64 + lane];
#pragma unroll
    for (int b = 0; b < 16; ++b) acc[b] += lq[b * 128 + r] * wv;
  }
#pragma unroll
  for (int b = 0; b < 16; ++b) red[wid][b][lane] = acc[b];
  __syncthreads();
#pragma unroll
  for (int it = 0; it < 4; ++it) {
    int idx = tid + it * 256;
    float s = red[0][idx >> 6][idx & 63] + red[1][idx >> 6][idx & 63] +
              red[2][idx >> 6][idx & 63] + red[3][idx >> 6][idx & 63];
    pqs[(size_t)blockIdx.x * 1024 + idx] = s;
  }
}

// Fused tail: qs-reduce + xmn-reduce + qt + attn + ets  (one block per batch b)
__global__ __launch_bounds__(256) void k_post(const float* __restrict__ pqs,
                                              const float* __restrict__ pxmn,
                                              const float* __restrict__ W_Q0,
                                              const float* __restrict__ W_QT,
                                              const float* __restrict__ K_T,
                                              const float* __restrict__ K_S,
                                              const float* __restrict__ V_T,
                                              const float* __restrict__ V_S,
                                              unsigned short* __restrict__ ets_bf) {
  const int b = blockIdx.x, tid = threadIdx.x;
  __shared__ float red[4][64];
  __shared__ float qs_s[64];
  __shared__ float qt_s[64];
  __shared__ float xmn_s[384];
  __shared__ float xp[384];
  __shared__ float at_s[8];

  {
    float s = 0.f;
    for (int c = tid >> 6; c < 512; c += 4) s += pqs[(size_t)c * 1024 + b * 64 + (tid & 63)];
    red[tid >> 6][tid & 63] = s;
  }
  for (int i = tid; i < 384; i += 256) {
    float v = pxmn[((0 + b) * 12) * 32 + i] + pxmn[((16 + b) * 12) * 32 + i] +
              pxmn[((32 + b) * 12) * 32 + i] + pxmn[((48 + b) * 12) * 32 + i];
    xmn_s[i] = v * (1.0f / 2048.0f);
  }
  __syncthreads();
  for (int i = tid; i < 384; i += 256) {
    int t = i >> 5, q = i & 31;
    float a = 0.f;
#pragma unroll
    for (int k = 0; k < 32; ++k) a += xmn_s[t * 32 + k] * W_Q0[k * 32 + q];
    xp[i] = a;
  }
  if (tid < 64) qs_s[tid] = red[0][tid] + red[1][tid] + red[2][tid] + red[3][tid];
  __syncthreads();
  if (tid < 64) {
    float q = 0.f;
    for (int i = 0; i < 384; ++i) q += xp[i] * W_QT[i * 64 + tid];
    qt_s[tid] = q;
  }
  __syncthreads();
  if (tid < 64) {
    int lane = tid;
    float qsv = qs_s[lane], qtv = qt_s[lane];
    float lt[4], ls[4];
#pragma unroll
    for (int h = 0; h < 4; ++h) {
      float p = qtv * K_T[h * 64 + lane];
#pragma unroll
      for (int off = 32; off > 0; off >>= 1) p += __shfl_xor(p, off);
      lt[h] = p;
      float p2 = qsv * K_S[h * 64 + lane];
#pragma unroll
      for (int off = 32; off > 0; off >>= 1) p2 += __shfl_xor(p2, off);
      ls[h] = p2;
    }
    if (lane == 0) {
      const float scale = 0.125f;
      float mt = fmaxf(fmaxf(lt[0], lt[1]), fmaxf(lt[2], lt[3]));
      float ms = fmaxf(fmaxf(ls[0], ls[1]), fmaxf(ls[2], ls[3]));
      float et[4], es[4], st = 0.f, ss = 0.f;
#pragma unroll
      for (int h = 0; h < 4; ++h) {
        et[h] = __expf((lt[h] - mt) * scale); st += et[h];
        es[h] = __expf((ls[h] - ms) * scale); ss += es[h];
      }
#pragma unroll
      for (int h = 0; h < 4; ++h) {
        at_s[h] = et[h] / st;
        at_s[4 + h] = es[h] / ss;
      }
    }
  }
  __syncthreads();
  float a0 = at_s[0], a1 = at_s[1], a2 = at_s[2], a3 = at_s[3];
  float s0 = at_s[4], s1 = at_s[5], s2 = at_s[6], s3 = at_s[7];
  for (int n = tid; n < 2048; n += 256) {
    float v[10];
#pragma unroll
    for (int c = 0; c < 10; ++c) {
      int o = n * 10 + c;
      v[c] = a0 * V_T[o] + a1 * V_T[20480 + o] + a2 * V_T[40960 + o] + a3 * V_T[61440 + o] +
             s0 * V_S[o] + s1 * V_S[20480 + o] + s2 * V_S[40960 + o] + s3 * V_S[61440 + o];
    }
    uint4 lo, hi;
    lo.x = (unsigned)f2bf(v[0]) | ((unsigned)f2bf(v[1]) << 16);
    lo.y = (unsigned)f2bf(v[2]) | ((unsigned)f2bf(v[3]) << 16);
    lo.z = (unsigned)f2bf(v[4]) | ((unsigned)f2bf(v[5]) << 16);
    lo.w = (unsigned)f2bf(v[6]) | ((unsigned)f2bf(v[7]) << 16);
    hi.x = (unsigned)f2bf(v[8]) | ((unsigned)f2bf(v[9]) << 16);
    hi.y = 0; hi.z = 0; hi.w = 0;
    size_t idx = (size_t)b * 2048 + n;
    *(uint4*)(ets_bf + idx * 16) = lo;
    *(uint4*)(ets_bf + idx * 16 + 8) = hi;
  }
}

// ---------------- phase B: MFMA adjacency + row softmax -> fp8 (x256, k-permuted) -----

__global__ __launch_bounds__(512, 4) void k_adj(const unsigned short* __restrict__ ets_bf,
                                                const float* __restrict__ dis,
                                                unsigned char* __restrict__ adjf) {
  __shared__ __align__(16) unsigned char Bsh[65536];
  __shared__ float st_max[8][16];
  __shared__ float st_sum[8][16];
  __shared__ float rowmax_s[16];
  __shared__ float rowinv_s[16];

  const int tid = threadIdx.x;
  const int lane = tid & 63;
  const int w = tid >> 6;
  const int cl = lane & 15;
  const int g = lane >> 4;
  const int b = blockIdx.x >> 7;
  const int n0 = (blockIdx.x & 127) << 4;

  const unsigned char* gsrc = (const unsigned char*)(ets_bf + (size_t)b * 32768);
#pragma unroll
  for (int it = 0; it < 8; ++it)
    gload16(gsrc + it * 8192 + tid * 16, Bsh + it * 8192 + (w << 10));
  __syncthreads();

  uint4 araw = *(const uint4*)(ets_bf + ((size_t)b * 2048 + n0 + cl) * 16 + (g & 1) * 8);
  if (g >= 2) { araw.x = 0; araw.y = 0; araw.z = 0; araw.w = 0; }
  bf16x8 afrag = __builtin_bit_cast(bf16x8, araw);

  f32x4 acc[16];
  const int cbase = (w << 8) + cl;
#pragma unroll
  for (int n = 0; n < 16; ++n) {
    uint4 braw = *(const uint4*)(Bsh + (size_t)(cbase + n * 16) * 32 + (g & 1) * 16);
    if (g >= 2) { braw.x = 0; braw.y = 0; braw.z = 0; braw.w = 0; }
    bf16x8 bfrag = __builtin_bit_cast(bf16x8, braw);
    acc[n] = __builtin_amdgcn_mfma_f32_16x16x32_bf16(afrag, bfrag, (f32x4){0.f, 0.f, 0.f, 0.f},
                                                     0, 0, 0);
  }

  float mx[4] = {-1e30f, -1e30f, -1e30f, -1e30f};
  const float* dbase = dis + (size_t)(n0 + g * 4) * 2048 + (w << 8) + cl;
#pragma unroll
  for (int n = 0; n < 16; ++n) {
#pragma unroll
    for (int j = 0; j < 4; ++j) {
      float s = fmaxf(acc[n][j] + dbase[(size_t)j * 2048 + n * 16], 0.f);
      acc[n][j] = s;
      mx[j] = fmaxf(mx[j], s);
    }
  }
#pragma unroll
  for (int j = 0; j < 4; ++j) {
    mx[j] = fmaxf(mx[j], __shfl_xor(mx[j], 1));
    mx[j] = fmaxf(mx[j], __shfl_xor(mx[j], 2));
    mx[j] = fmaxf(mx[j], __shfl_xor(mx[j], 4));
    mx[j] = fmaxf(mx[j], __shfl_xor(mx[j], 8));
  }
  if (cl == 0) {
#pragma unroll
    for (int j = 0; j < 4; ++j) st_max[w][g * 4 + j] = mx[j];
  }
  __syncthreads();
  if (tid < 16) {
    float m = st_max[0][tid];
#pragma unroll
    for (int ww = 1; ww < 8; ++ww) m = fmaxf(m, st_max[ww][tid]);
    rowmax_s[tid] = m;
  }
  __syncthreads();

  float rm[4], sm[4] = {0.f, 0.f, 0.f, 0.f};
#pragma unroll
  for (int j = 0; j < 4; ++j) rm[j] = rowmax_s[g * 4 + j];
#pragma unroll
  for (int n = 0; n < 16; ++n) {
#pragma unroll
    for (int j = 0; j < 4; ++j) {
      float e = __expf(acc[n][j] - rm[j]);
      acc[n][j] = e;
      sm[j] += e;
    }
  }
#pragma unroll
  for (int j = 0; j < 4; ++j) {
    sm[j] += __shfl_xor(sm[j], 1);
    sm[j] += __shfl_xor(sm[j], 2);
    sm[j] += __shfl_xor(sm[j], 4);
    sm[j] += __shfl_xor(sm[j], 8);
  }
  if (cl == 0) {
#pragma unroll
    for (int j = 0; j < 4; ++j) st_sum[w][g * 4 + j] = sm[j];
  }
  __syncthreads();
  if (tid < 16) {
    float s = st_sum[0][tid];
#pragma unroll
    for (int ww = 1; ww < 8; ++ww) s += st_sum[ww][tid];
    rowinv_s[tid] = 256.0f / s;  // x256 so fp8 stays in normal range
  }
  __syncthreads();  // all Bsh B-reads done -> safe to reuse as transpose buf

  unsigned char* Tw = Bsh + (w << 12);
  float inv[4];
#pragma unroll
  for (int j = 0; j < 4; ++j) inv[j] = rowinv_s[g * 4 + j];
#pragma unroll
  for (int n = 0; n < 16; ++n) {
    int ml = n * 16 + cl;
    int pb = ((ml >> 7) << 7) + perm7(ml & 127);
#pragma unroll
    for (int j = 0; j < 4; ++j)
      Tw[(g * 4 + j) * 256 + pb] = f2fp8(acc[n][j] * inv[j]);
  }
  __syncthreads();

  unsigned char* obase = adjf + ((size_t)b * 2048 + n0) * 2048 + (w << 8);
#pragma unroll
  for (int r = 0; r < 16; ++r) {
    unsigned v = *(const unsigned*)(Tw + r * 256 + lane * 4);
    *(unsigned*)(obase + (size_t)r * 2048 + lane * 4) = v;
  }
}

// ---------------- phase C producer: MFMA x @ {W2,Ws0,Ws1} ----------------
// [393216 x 32] @ [32 x 96] via mfma_16x16x32_bf16. Outputs transposed:
// z0Tf[t*32+d][perm(m)] fp8; bias{0,1}T[t*32+d][m] bf16.

__global__ __launch_bounds__(256) void k_zb(const float* __restrict__ x,
                                            const float* __restrict__ W2,
                                            const float* __restrict__ Ws0,
                                            const float* __restrict__ Ws1,
                                            unsigned char* __restrict__ z0Tf,
                                            unsigned short* __restrict__ bias0T,
                                            unsigned short* __restrict__ bias1T) {
  __shared__ __align__(16) unsigned short wlds[3072];  // [mat*32+d][k] bf16
  const int tid = threadIdx.x;
  for (int j = tid; j < 3072; j += 256) {
    int mat = j >> 10, r = j & 1023, k = r >> 5, d = r & 31;
    const float* Wsrc = (mat == 0) ? W2 : (mat == 1 ? Ws0 : Ws1);
    wlds[(mat * 32 + d) * 32 + k] = f2bf(Wsrc[r]);
  }
  __syncthreads();

  const int lane = tid & 63, w = tid >> 6;
  const int cl = lane & 15, g = lane >> 4;
  const int bx = blockIdx.x;
  const int b = bx / 48, r = bx % 48, t = r >> 2, mc = r & 3;
  const int m0w = mc * 512 + w * 128;

  bf16x8 bfr[6];
#pragma unroll
  for (int dt = 0; dt < 6; ++dt)
    bfr[dt] = *(const bf16x8*)(wlds + (dt * 16 + cl) * 32 + g * 8);

  const float* gx = x + ((size_t)(b * 2048 + m0w + cl) * 12 + t) * 32 + g * 8;
  unsigned char* z0base = z0Tf + (size_t)b * 786432 + (size_t)(t * 32) * 2048;
  unsigned short* b0base = bias0T + (size_t)b * 786432 + (size_t)(t * 32) * 2048;
  unsigned short* b1base = bias1T + (size_t)b * 786432 + (size_t)(t * 32) * 2048;

#pragma unroll
  for (int i = 0; i < 8; ++i) {
    const float* xp = gx + (size_t)i * 16 * 384;
    float4 v0 = *(const float4*)xp;
    float4 v1 = *(const float4*)(xp + 4);
    bf16x8 af;
    af[0] = (__bf16)v0.x; af[1] = (__bf16)v0.y; af[2] = (__bf16)v0.z; af[3] = (__bf16)v0.w;
    af[4] = (__bf16)v1.x; af[5] = (__bf16)v1.y; af[6] = (__bf16)v1.z; af[7] = (__bf16)v1.w;
    f32x4 acc[6];
#pragma unroll
    for (int dt = 0; dt < 6; ++dt)
      acc[dt] = __builtin_amdgcn_mfma_f32_16x16x32_bf16(af, bfr[dt],
                                                        (f32x4){0.f, 0.f, 0.f, 0.f}, 0, 0, 0);
    const int m = m0w + i * 16 + g * 4;  // 4 consecutive m-rows this lane owns
    const int pb = ((m >> 7) << 7) + perm7(m & 127);
#pragma unroll
    for (int dt = 0; dt < 2; ++dt) {
      unsigned u = __builtin_amdgcn_cvt_pk_fp8_f32(acc[dt][0], acc[dt][1], 0, false);
      u = __builtin_amdgcn_cvt_pk_fp8_f32(acc[dt][2], acc[dt][3], (int)u, true);
      *(unsigned*)(z0base + (size_t)(dt * 16 + cl) * 2048 + pb) = u;
    }
#pragma unroll
    for (int dt = 0; dt < 2; ++dt) {
      uint2 p;
      p.x = (unsigned)f2bf(acc[2 + dt][0]) | ((unsigned)f2bf(acc[2 + dt][1]) << 16);
      p.y = (unsigned)f2bf(acc[2 + dt][2]) | ((unsigned)f2bf(acc[2 + dt][3]) << 16);
      *(uint2*)(b0base + (size_t)(dt * 16 + cl) * 2048 + m) = p;
      uint2 q;
      q.x = (unsigned)f2bf(acc[4 + dt][0]) | ((unsigned)f2bf(acc[4 + dt][1]) << 16);
      q.y = (unsigned)f2bf(acc[4 + dt][2]) | ((unsigned)f2bf(acc[4 + dt][3]) << 16);
      *(uint2*)(b1base + (size_t)(dt * 16 + cl) * 2048 + m) = q;
    }
  }
}

// ---------------- phase C: (adj*256) @ z fp8 MFMA GEMM ----------------
// 128x192 tile, BK=128 (fp8, k-permuted layout), counted-vmcnt double buffer,
// 512 blocks = 2/CU, XCD-bijective swizzle. Bias read from transposed [384][2048] bf16.

template <int OUT_F32>
__global__ __launch_bounds__(256, 2) void gemm_adj(const unsigned char* __restrict__ adjf,
                                                   const unsigned char* __restrict__ Bt,
                                                   const unsigned short* __restrict__ biasT,
                                                   void* __restrict__ outp) {
  const int tid = threadIdx.x;
  const int lane = tid & 63;
  const int wid = tid >> 6;
  const int wr = wid >> 1, wc = wid & 1;
  const int orig = blockIdx.x;
  const int wg = (orig & 7) * 64 + (orig >> 3);
  const int b = wg >> 5;
  const int w32 = wg & 31;
  const int m0 = ((w32 >> 1) & 15) << 7;
  const int c0 = (w32 & 1) * 192;

  __shared__ __align__(16) unsigned char smem[81920];

  const unsigned char* aBase = adjf + ((size_t)b << 22);
  const unsigned char* bBase = Bt + (size_t)b * 786432;
  const int jx = ((tid & 7) ^ ((tid >> 3) & 7)) << 4;
  const unsigned char* gA = aBase + (size_t)(m0 + (tid >> 3)) * 2048 + jx;
  const unsigned char* gB = bBase + (size_t)(c0 + (tid >> 3)) * 2048 + jx;

  int aoff[2][4], boff[2][6];
#pragma unroll
  for (int kkp = 0; kkp < 2; ++kkp) {
    int c = ((lane >> 4) << 1) + kkp;
#pragma unroll
    for (int f = 0; f < 4; ++f) {
      int rA = wr * 64 + f * 16 + (lane & 15);
      aoff[kkp][f] = rA * 128 + ((c ^ (rA & 7)) << 4);
    }
#pragma unroll
    for (int n = 0; n < 6; ++n) {
      int rB = wc * 96 + n * 16 + (lane & 15);
      boff[kkp][n] = 16384 + rB * 128 + ((c ^ (rB & 7)) << 4);
    }
  }

  f32x4 acc[4][6] = {};

#define STAGE(BUF, KT)                                                               \
  {                                                                                  \
    _Pragma("unroll") for (int ii = 0; ii < 4; ++ii)                                 \
        gload16(gA + (size_t)ii * 65536 + (KT)*128, smem + (BUF) + ii * 4096 + tid * 16); \
    _Pragma("unroll") for (int ii = 0; ii < 6; ++ii)                                 \
        gload16(gB + (size_t)ii * 65536 + (KT)*128,                                  \
                smem + (BUF) + 16384 + ii * 4096 + tid * 16);                        \
  }

  STAGE(0, 0);

  int cur = 0;
  for (int kt = 0; kt < 16; ++kt) {
    const int nxt = cur ^ 40960;
    if (kt < 15) {
      STAGE(nxt, kt + 1);
      asm volatile("s_waitcnt vmcnt(10)" ::: "memory");
    } else {
      asm volatile("s_waitcnt vmcnt(0)" ::: "memory");
    }
    __builtin_amdgcn_s_barrier();
#pragma unroll
    for (int kkp = 0; kkp < 2; ++kkp) {
      ulong2 av[4], bv[6];
#pragma unroll
      for (int f = 0; f < 4; ++f) av[f] = *(const ulong2*)(smem + cur + aoff[kkp][f]);
#pragma unroll
      for (int n = 0; n < 6; ++n) bv[n] = *(const ulong2*)(smem + cur + boff[kkp][n]);
#pragma unroll
      for (int m = 0; m < 4; ++m)
#pragma unroll
        for (int n = 0; n < 6; ++n)
          acc[m][n] = __builtin_amdgcn_mfma_f32_16x16x32_fp8_fp8(
              (long)av[m].x, (long)bv[n].x, acc[m][n], 0, 0, 0);
#pragma unroll
      for (int m = 0; m < 4; ++m)
#pragma unroll
        for (int n = 0; n < 6; ++n)
          acc[m][n] = __builtin_amdgcn_mfma_f32_16x16x32_fp8_fp8(
              (long)av[m].y, (long)bv[n].y, acc[m][n], 0, 0, 0);
    }
    __builtin_amdgcn_s_barrier();
    cur = nxt;
  }
#undef STAGE

  const float inv256 = 0.00390625f;
  const int cl = lane & 15;
  const int r4 = (lane >> 4) << 2;
  const unsigned short* bi = biasT + (size_t)b * 786432;
  if (OUT_F32) {
    float* o = (float*)outp + (size_t)b * 786432;
#pragma unroll
    for (int m = 0; m < 4; ++m) {
      int row0 = m0 + wr * 64 + m * 16 + r4;
#pragma unroll
      for (int n = 0; n < 6; ++n) {
        int col = c0 + wc * 96 + n * 16 + cl;
        uint2 bw = *(const uint2*)(bi + ((size_t)col << 11) + row0);
        float bv0 = bf2f((unsigned short)(bw.x & 0xffff));
        float bv1 = bf2f((unsigned short)(bw.x >> 16));
        float bv2 = bf2f((unsigned short)(bw.y & 0xffff));
        float bv3 = bf2f((unsigned short)(bw.y >> 16));
        o[(size_t)(row0 + 0) * 384 + col] = acc[m][n][0] * inv256 + bv0;
        o[(size_t)(row0 + 1) * 384 + col] = acc[m][n][1] * inv256 + bv1;
        o[(size_t)(row0 + 2) * 384 + col] = acc[m][n][2] * inv256 + bv2;
        o[(size_t)(row0 + 3) * 384 + col] = acc[m][n][3] * inv256 + bv3;
      }
    }
  } else {
    unsigned char* o = (unsigned char*)outp + (size_t)b * 786432;
#pragma unroll
    for (int m = 0; m < 4; ++m) {
      int row0 = m0 + wr * 64 + m * 16 + r4;
      const int pb = ((row0 >> 7) << 7) + perm7(row0 & 127);
#pragma unroll
      for (int n = 0; n < 6; ++n) {
        int col = c0 + wc * 96 + n * 16 + cl;
        uint2 bw = *(const uint2*)(bi + ((size_t)col << 11) + row0);
        float v0 = acc[m][n][0] * inv256 + bf2f((unsigned short)(bw.x & 0xffff));
        float v1 = acc[m][n][1] * inv256 + bf2f((unsigned short)(bw.x >> 16));
        float v2 = acc[m][n][2] * inv256 + bf2f((unsigned short)(bw.y & 0xffff));
        float v3 = acc[m][n][3] * inv256 + bf2f((unsigned short)(bw.y >> 16));
        unsigned u = __builtin_amdgcn_cvt_pk_fp8_f32(v0, v1, 0, false);
        u = __builtin_amdgcn_cvt_pk_fp8_f32(v2, v3, (int)u, true);
        *(unsigned*)(o + (size_t)col * 2048 + pb) = u;
      }
    }
  }
}

// ---------------- launch ----------------

extern "C" void kernel_launch(void* const* d_in, const int* in_sizes, int n_in,
                              void* d_out, int out_size, void* d_ws, size_t ws_size,
                              hipStream_t stream) {
  const float* x = (const float*)d_in[0];
  const float* dis = (const float*)d_in[1];
  const float* K_S = (const float*)d_in[2];
  const float* V_S = (const float*)d_in[3];
  const float* K_T = (const float*)d_in[4];
  const float* V_T = (const float*)d_in[5];
  const float* W_Q0 = (const float*)d_in[6];
  const float* W_QS = (const float*)d_in[7];
  const float* W_QT = (const float*)d_in[8];
  const float* W2 = (const float*)d_in[9];
  const float* W_s0 = (const float*)d_in[10];
  const float* W_s1 = (const float*)d_in[11];

  char* ws = (char*)d_ws;
  float* pxmn = (float*)(ws + 0);                            //     98,304 B
  float* pqs = (float*)(ws + 98304);                         //  2,097,152 B
  unsigned short* ets_bf = (unsigned short*)(ws + 2195456);  //  1,048,576 B
  unsigned char* adjf = (unsigned char*)(ws + 3244032);      // 67,108,864 B
  unsigned char* z0Tf = (unsigned char*)(ws + 70352896);     // 12,582,912 B
  unsigned char* z1Tf = (unsigned char*)(ws + 82935808);     // 12,582,912 B
  unsigned short* bias0T = (unsigned short*)(ws + 95518720); // 25,165,824 B
  unsigned short* bias1T = (unsigned short*)(ws + 120684544);// 25,165,824 B

  k_xmn<<<768, 256, 0, stream>>>(x, pxmn);
  k_qs<<<512, 256, 0, stream>>>(x, W_Q0, W_QS, pqs);
  k_post<<<16, 256, 0, stream>>>(pqs, pxmn, W_Q0, W_QT, K_T, K_S, V_T, V_S, ets_bf);
  k_adj<<<2048, 512, 0, stream>>>(ets_bf, dis, adjf);
  k_zb<<<768, 256, 0, stream>>>(x, W2, W_s0, W_s1, z0Tf, bias0T, bias1T);
  gemm_adj<0><<<512, 256, 0, stream>>>(adjf, z0Tf, bias0T, (void*)z1Tf);
  gemm_adj<1><<<512, 256, 0, stream>>>(adjf, z1Tf, bias1T, d_out);
}

// Round 11
// 232.124 us; speedup vs baseline: 2.2190x; 1.2494x over previous
//
#include <hip/hip_runtime.h>

typedef __bf16 bf16x8 __attribute__((ext_vector_type(8)));
typedef float f32x4 __attribute__((ext_vector_type(4)));

__device__ __forceinline__ unsigned short f2bf(float f) {
  unsigned u = __builtin_bit_cast(unsigned, f);
  u += 0x7fffu + ((u >> 16) & 1u);
  return (unsigned short)(u >> 16);
}
__device__ __forceinline__ float bf2f(unsigned short h) {
  unsigned u = ((unsigned)h) << 16;
  return __builtin_bit_cast(float, u);
}
__device__ __forceinline__ unsigned char f2fp8(float v) {
  return (unsigned char)(__builtin_amdgcn_cvt_pk_fp8_f32(v, v, 0, false) & 0xff);
}
__device__ __forceinline__ void gload16(const void* g, void* l) {
  __builtin_amdgcn_global_load_lds((const __attribute__((address_space(1))) void*)g,
                                   (__attribute__((address_space(3))) void*)l, 16, 0, 0);
}
// byte permutation within a 128-byte K-panel row: k = kk*32+g*8+e -> byte g*32+kk*8+e
__device__ __forceinline__ int perm7(int x) {
  return ((x >> 3) & 3) * 32 + ((x >> 5) << 3) + (x & 7);
}

// ---------------- phase A ----------------

// pxmn[c,b,t,k] = sum over n-chunk c of x[b,:,t,k]   (768 blocks = 3/CU)
__global__ __launch_bounds__(256) void k_xmn(const float* __restrict__ x,
                                             float* __restrict__ pxmn) {
  int bx = blockIdx.x;
  int b = bx / 48, r = bx % 48, t = r >> 2, c = r & 3;
  int k = threadIdx.x & 31, sl = threadIdx.x >> 5;
  const float* xp = x + (size_t)b * 786432 + (size_t)(c * 512) * 384 + (size_t)t * 32 + k;
  float s = 0.f;
  for (int i = 0; i < 64; ++i) s += xp[(size_t)((sl << 6) + i) * 384];
  __shared__ float red[8][32];
  red[sl][k] = s;
  __syncthreads();
  if (threadIdx.x < 32) {
    float tot = 0.f;
#pragma unroll
    for (int j = 0; j < 8; ++j) tot += red[j][threadIdx.x];
    pxmn[((c * 16 + b) * 12 + t) * 32 + threadIdx.x] = tot;
  }
}

// Fused: per block (4 n-values): mean_t(x) -> @W_Q0 -> contract with W_QS rows
__global__ __launch_bounds__(256) void k_qs(const float* __restrict__ x,
                                            const float* __restrict__ W_Q0,
                                            const float* __restrict__ W_QS,
                                            float* __restrict__ pqs) {
  __shared__ __align__(16) float w0[1024];
  __shared__ float lm[2048];
  __shared__ float lq[2048];
  __shared__ float red[4][16][64];
  int tid = threadIdx.x;
#pragma unroll
  for (int i = 0; i < 4; ++i) w0[tid + i * 256] = W_Q0[tid + i * 256];
  int n0 = blockIdx.x * 4;
#pragma unroll
  for (int j = 0; j < 8; ++j) {
    int i = tid + j * 256;
    int b = i >> 7, r = i & 127;
    int n = n0 + (r >> 5), k = r & 31;
    const float* xp = x + ((size_t)(b * 2048 + n) * 12) * 32 + k;
    float s = 0.f;
#pragma unroll
    for (int t = 0; t < 12; ++t) s += xp[t * 32];
    lm[i] = s * (1.0f / 12.0f);
  }
  __syncthreads();
#pragma unroll
  for (int j = 0; j < 8; ++j) {
    int i = tid + j * 256;
    int br = i >> 5, q = i & 31;
    const float* mrow = &lm[br * 32];
    float a = 0.f;
#pragma unroll
    for (int k = 0; k < 32; ++k) a += mrow[k] * w0[k * 32 + q];
    lq[i] = a;
  }
  __syncthreads();
  int lane = tid & 63, wid = tid >> 6;
  float acc[16];
#pragma unroll
  for (int b = 0; b < 16; ++b) acc[b] = 0.f;
  for (int rl = 0; rl < 32; ++rl) {
    int r = wid * 32 + rl;
    float wv = W_QS[(size_t)(n0 * 32 + r) * 64 + lane];
#pragma unroll
    for (int b = 0; b < 16; ++b) acc[b] += lq[b * 128 + r] * wv;
  }
#pragma unroll
  for (int b = 0; b < 16; ++b) red[wid][b][lane] = acc[b];
  __syncthreads();
#pragma unroll
  for (int it = 0; it < 4; ++it) {
    int idx = tid + it * 256;
    float s = red[0][idx >> 6][idx & 63] + red[1][idx >> 6][idx & 63] +
              red[2][idx >> 6][idx & 63] + red[3][idx >> 6][idx & 63];
    pqs[(size_t)blockIdx.x * 1024 + idx] = s;
  }
}

// Head-attention weights: pqs/pxmn reduce + qt + softmax -> at_g[16][8]
__global__ __launch_bounds__(256) void k_head(const float* __restrict__ pqs,
                                              const float* __restrict__ pxmn,
                                              const float* __restrict__ W_Q0,
                                              const float* __restrict__ W_QT,
                                              const float* __restrict__ K_T,
                                              const float* __restrict__ K_S,
                                              float* __restrict__ at_g) {
  const int b = blockIdx.x, tid = threadIdx.x;
  __shared__ float red[4][64];
  __shared__ float qs_s[64];
  __shared__ float xmn_s[384];
  __shared__ float xp[384];
  __shared__ float qtp[4][64];

  // pqs reduce: 4 independent accumulators, 4 loads in flight
  {
    const int q = tid >> 6, dk = tid & 63;
    const float* p = pqs + (size_t)(q * 128) * 1024 + b * 64 + dk;
    float s0 = 0.f, s1 = 0.f, s2 = 0.f, s3 = 0.f;
#pragma unroll
    for (int c = 0; c < 128; c += 4) {
      s0 += p[(size_t)(c + 0) * 1024];
      s1 += p[(size_t)(c + 1) * 1024];
      s2 += p[(size_t)(c + 2) * 1024];
      s3 += p[(size_t)(c + 3) * 1024];
    }
    red[q][dk] = (s0 + s1) + (s2 + s3);
  }
  for (int i = tid; i < 384; i += 256) {
    float v = pxmn[(b * 12) * 32 + i] + pxmn[((16 + b) * 12) * 32 + i] +
              pxmn[((32 + b) * 12) * 32 + i] + pxmn[((48 + b) * 12) * 32 + i];
    xmn_s[i] = v * (1.0f / 2048.0f);
  }
  __syncthreads();
  // xp = (xmn @ W_Q0), flattened
  for (int i = tid; i < 384; i += 256) {
    int t = i >> 5, q = i & 31;
    float a = 0.f;
#pragma unroll
    for (int k = 0; k < 32; ++k) a += xmn_s[t * 32 + k] * W_Q0[k * 32 + q];
    xp[i] = a;
  }
  if (tid < 64) qs_s[tid] = red[0][tid] + red[1][tid] + red[2][tid] + red[3][tid];
  __syncthreads();
  // qt partials: wave w covers i in [w*96, w*96+96), 3 accumulators
  {
    const int w = tid >> 6, dk = tid & 63;
    const float* wq = W_QT + (size_t)(w * 96) * 64 + dk;
    const float* xw = xp + w * 96;
    float a0 = 0.f, a1 = 0.f, a2 = 0.f;
#pragma unroll
    for (int i = 0; i < 96; i += 3) {
      a0 += xw[i + 0] * wq[(size_t)(i + 0) * 64];
      a1 += xw[i + 1] * wq[(size_t)(i + 1) * 64];
      a2 += xw[i + 2] * wq[(size_t)(i + 2) * 64];
    }
    qtp[w][dk] = (a0 + a1) + a2;
  }
  __syncthreads();
  if (tid < 64) {
    int lane = tid;
    float qtv = qtp[0][lane] + qtp[1][lane] + qtp[2][lane] + qtp[3][lane];
    float qsv = qs_s[lane];
    float lt[4], ls[4];
#pragma unroll
    for (int h = 0; h < 4; ++h) {
      float p = qtv * K_T[h * 64 + lane];
#pragma unroll
      for (int off = 32; off > 0; off >>= 1) p += __shfl_xor(p, off);
      lt[h] = p;
      float p2 = qsv * K_S[h * 64 + lane];
#pragma unroll
      for (int off = 32; off > 0; off >>= 1) p2 += __shfl_xor(p2, off);
      ls[h] = p2;
    }
    if (lane == 0) {
      const float scale = 0.125f;
      float mt = fmaxf(fmaxf(lt[0], lt[1]), fmaxf(lt[2], lt[3]));
      float ms = fmaxf(fmaxf(ls[0], ls[1]), fmaxf(ls[2], ls[3]));
      float et[4], es[4], st = 0.f, ss = 0.f;
#pragma unroll
      for (int h = 0; h < 4; ++h) {
        et[h] = __expf((lt[h] - mt) * scale); st += et[h];
        es[h] = __expf((ls[h] - ms) * scale); ss += es[h];
      }
#pragma unroll
      for (int h = 0; h < 4; ++h) {
        at_g[b * 8 + h] = et[h] / st;
        at_g[b * 8 + 4 + h] = es[h] / ss;
      }
    }
  }
}

// ets_bf[b][n][16] (k>=10 zero) from attention-mixed V  (128 blocks)
__global__ __launch_bounds__(256) void k_ets(const float* __restrict__ at_g,
                                             const float* __restrict__ V_T,
                                             const float* __restrict__ V_S,
                                             unsigned short* __restrict__ ets_bf) {
  int idx = blockIdx.x * 256 + threadIdx.x;
  int b = idx >> 11, n = idx & 2047;
  const float* at = at_g + b * 8;
  float a0 = at[0], a1 = at[1], a2 = at[2], a3 = at[3];
  float s0 = at[4], s1 = at[5], s2 = at[6], s3 = at[7];
  float v[10];
#pragma unroll
  for (int c = 0; c < 10; ++c) {
    int o = n * 10 + c;
    v[c] = a0 * V_T[o] + a1 * V_T[20480 + o] + a2 * V_T[40960 + o] + a3 * V_T[61440 + o] +
           s0 * V_S[o] + s1 * V_S[20480 + o] + s2 * V_S[40960 + o] + s3 * V_S[61440 + o];
  }
  uint4 lo, hi;
  lo.x = (unsigned)f2bf(v[0]) | ((unsigned)f2bf(v[1]) << 16);
  lo.y = (unsigned)f2bf(v[2]) | ((unsigned)f2bf(v[3]) << 16);
  lo.z = (unsigned)f2bf(v[4]) | ((unsigned)f2bf(v[5]) << 16);
  lo.w = (unsigned)f2bf(v[6]) | ((unsigned)f2bf(v[7]) << 16);
  hi.x = (unsigned)f2bf(v[8]) | ((unsigned)f2bf(v[9]) << 16);
  hi.y = 0; hi.z = 0; hi.w = 0;
  *(uint4*)(ets_bf + (size_t)idx * 16) = lo;
  *(uint4*)(ets_bf + (size_t)idx * 16 + 8) = hi;
}

// ---------------- phase B: MFMA adjacency + row softmax -> fp8 (x256, k-permuted) -----

__global__ __launch_bounds__(512, 4) void k_adj(const unsigned short* __restrict__ ets_bf,
                                                const float* __restrict__ dis,
                                                unsigned char* __restrict__ adjf) {
  __shared__ __align__(16) unsigned char Bsh[65536];
  __shared__ float st_max[8][16];
  __shared__ float st_sum[8][16];
  __shared__ float rowmax_s[16];
  __shared__ float rowinv_s[16];

  const int tid = threadIdx.x;
  const int lane = tid & 63;
  const int w = tid >> 6;
  const int cl = lane & 15;
  const int g = lane >> 4;
  const int b = blockIdx.x >> 7;
  const int n0 = (blockIdx.x & 127) << 4;

  const unsigned char* gsrc = (const unsigned char*)(ets_bf + (size_t)b * 32768);
#pragma unroll
  for (int it = 0; it < 8; ++it)
    gload16(gsrc + it * 8192 + tid * 16, Bsh + it * 8192 + (w << 10));
  __syncthreads();

  uint4 araw = *(const uint4*)(ets_bf + ((size_t)b * 2048 + n0 + cl) * 16 + (g & 1) * 8);
  if (g >= 2) { araw.x = 0; araw.y = 0; araw.z = 0; araw.w = 0; }
  bf16x8 afrag = __builtin_bit_cast(bf16x8, araw);

  f32x4 acc[16];
  const int cbase = (w << 8) + cl;
#pragma unroll
  for (int n = 0; n < 16; ++n) {
    uint4 braw = *(const uint4*)(Bsh + (size_t)(cbase + n * 16) * 32 + (g & 1) * 16);
    if (g >= 2) { braw.x = 0; braw.y = 0; braw.z = 0; braw.w = 0; }
    bf16x8 bfrag = __builtin_bit_cast(bf16x8, braw);
    acc[n] = __builtin_amdgcn_mfma_f32_16x16x32_bf16(afrag, bfrag, (f32x4){0.f, 0.f, 0.f, 0.f},
                                                     0, 0, 0);
  }

  float mx[4] = {-1e30f, -1e30f, -1e30f, -1e30f};
  const float* dbase = dis + (size_t)(n0 + g * 4) * 2048 + (w << 8) + cl;
#pragma unroll
  for (int n = 0; n < 16; ++n) {
#pragma unroll
    for (int j = 0; j < 4; ++j) {
      float s = fmaxf(acc[n][j] + dbase[(size_t)j * 2048 + n * 16], 0.f);
      acc[n][j] = s;
      mx[j] = fmaxf(mx[j], s);
    }
  }
#pragma unroll
  for (int j = 0; j < 4; ++j) {
    mx[j] = fmaxf(mx[j], __shfl_xor(mx[j], 1));
    mx[j] = fmaxf(mx[j], __shfl_xor(mx[j], 2));
    mx[j] = fmaxf(mx[j], __shfl_xor(mx[j], 4));
    mx[j] = fmaxf(mx[j], __shfl_xor(mx[j], 8));
  }
  if (cl == 0) {
#pragma unroll
    for (int j = 0; j < 4; ++j) st_max[w][g * 4 + j] = mx[j];
  }
  __syncthreads();
  if (tid < 16) {
    float m = st_max[0][tid];
#pragma unroll
    for (int ww = 1; ww < 8; ++ww) m = fmaxf(m, st_max[ww][tid]);
    rowmax_s[tid] = m;
  }
  __syncthreads();

  float rm[4], sm[4] = {0.f, 0.f, 0.f, 0.f};
#pragma unroll
  for (int j = 0; j < 4; ++j) rm[j] = rowmax_s[g * 4 + j];
#pragma unroll
  for (int n = 0; n < 16; ++n) {
#pragma unroll
    for (int j = 0; j < 4; ++j) {
      float e = __expf(acc[n][j] - rm[j]);
      acc[n][j] = e;
      sm[j] += e;
    }
  }
#pragma unroll
  for (int j = 0; j < 4; ++j) {
    sm[j] += __shfl_xor(sm[j], 1);
    sm[j] += __shfl_xor(sm[j], 2);
    sm[j] += __shfl_xor(sm[j], 4);
    sm[j] += __shfl_xor(sm[j], 8);
  }
  if (cl == 0) {
#pragma unroll
    for (int j = 0; j < 4; ++j) st_sum[w][g * 4 + j] = sm[j];
  }
  __syncthreads();
  if (tid < 16) {
    float s = st_sum[0][tid];
#pragma unroll
    for (int ww = 1; ww < 8; ++ww) s += st_sum[ww][tid];
    rowinv_s[tid] = 256.0f / s;  // x256 so fp8 stays in normal range
  }
  __syncthreads();  // all Bsh B-reads done -> safe to reuse as transpose buf

  unsigned char* Tw = Bsh + (w << 12);
  float inv[4];
#pragma unroll
  for (int j = 0; j < 4; ++j) inv[j] = rowinv_s[g * 4 + j];
#pragma unroll
  for (int n = 0; n < 16; ++n) {
    int ml = n * 16 + cl;
    int pb = ((ml >> 7) << 7) + perm7(ml & 127);
#pragma unroll
    for (int j = 0; j < 4; ++j)
      Tw[(g * 4 + j) * 256 + pb] = f2fp8(acc[n][j] * inv[j]);
  }
  __syncthreads();

  unsigned char* obase = adjf + ((size_t)b * 2048 + n0) * 2048 + (w << 8);
#pragma unroll
  for (int r = 0; r < 16; ++r) {
    unsigned v = *(const unsigned*)(Tw + r * 256 + lane * 4);
    *(unsigned*)(obase + (size_t)r * 2048 + lane * 4) = v;
  }
}

// ---------------- phase C producer: MFMA x @ {W2,Ws0,Ws1} ----------------

__global__ __launch_bounds__(256) void k_zb(const float* __restrict__ x,
                                            const float* __restrict__ W2,
                                            const float* __restrict__ Ws0,
                                            const float* __restrict__ Ws1,
                                            unsigned char* __restrict__ z0Tf,
                                            unsigned short* __restrict__ bias0T,
                                            unsigned short* __restrict__ bias1T) {
  __shared__ __align__(16) unsigned short wlds[3072];  // [mat*32+d][k] bf16
  const int tid = threadIdx.x;
  for (int j = tid; j < 3072; j += 256) {
    int mat = j >> 10, r = j & 1023, k = r >> 5, d = r & 31;
    const float* Wsrc = (mat == 0) ? W2 : (mat == 1 ? Ws0 : Ws1);
    wlds[(mat * 32 + d) * 32 + k] = f2bf(Wsrc[r]);
  }
  __syncthreads();

  const int lane = tid & 63, w = tid >> 6;
  const int cl = lane & 15, g = lane >> 4;
  const int bx = blockIdx.x;
  const int b = bx / 48, r = bx % 48, t = r >> 2, mc = r & 3;
  const int m0w = mc * 512 + w * 128;

  bf16x8 bfr[6];
#pragma unroll
  for (int dt = 0; dt < 6; ++dt)
    bfr[dt] = *(const bf16x8*)(wlds + (dt * 16 + cl) * 32 + g * 8);

  const float* gx = x + ((size_t)(b * 2048 + m0w + cl) * 12 + t) * 32 + g * 8;
  unsigned char* z0base = z0Tf + (size_t)b * 786432 + (size_t)(t * 32) * 2048;
  unsigned short* b0base = bias0T + (size_t)b * 786432 + (size_t)(t * 32) * 2048;
  unsigned short* b1base = bias1T + (size_t)b * 786432 + (size_t)(t * 32) * 2048;

#pragma unroll
  for (int i = 0; i < 8; ++i) {
    const float* xp = gx + (size_t)i * 16 * 384;
    float4 v0 = *(const float4*)xp;
    float4 v1 = *(const float4*)(xp + 4);
    bf16x8 af;
    af[0] = (__bf16)v0.x; af[1] = (__bf16)v0.y; af[2] = (__bf16)v0.z; af[3] = (__bf16)v0.w;
    af[4] = (__bf16)v1.x; af[5] = (__bf16)v1.y; af[6] = (__bf16)v1.z; af[7] = (__bf16)v1.w;
    f32x4 acc[6];
#pragma unroll
    for (int dt = 0; dt < 6; ++dt)
      acc[dt] = __builtin_amdgcn_mfma_f32_16x16x32_bf16(af, bfr[dt],
                                                        (f32x4){0.f, 0.f, 0.f, 0.f}, 0, 0, 0);
    const int m = m0w + i * 16 + g * 4;
    const int pb = ((m >> 7) << 7) + perm7(m & 127);
#pragma unroll
    for (int dt = 0; dt < 2; ++dt) {
      unsigned u = __builtin_amdgcn_cvt_pk_fp8_f32(acc[dt][0], acc[dt][1], 0, false);
      u = __builtin_amdgcn_cvt_pk_fp8_f32(acc[dt][2], acc[dt][3], (int)u, true);
      *(unsigned*)(z0base + (size_t)(dt * 16 + cl) * 2048 + pb) = u;
    }
#pragma unroll
    for (int dt = 0; dt < 2; ++dt) {
      uint2 p;
      p.x = (unsigned)f2bf(acc[2 + dt][0]) | ((unsigned)f2bf(acc[2 + dt][1]) << 16);
      p.y = (unsigned)f2bf(acc[2 + dt][2]) | ((unsigned)f2bf(acc[2 + dt][3]) << 16);
      *(uint2*)(b0base + (size_t)(dt * 16 + cl) * 2048 + m) = p;
      uint2 q;
      q.x = (unsigned)f2bf(acc[4 + dt][0]) | ((unsigned)f2bf(acc[4 + dt][1]) << 16);
      q.y = (unsigned)f2bf(acc[4 + dt][2]) | ((unsigned)f2bf(acc[4 + dt][3]) << 16);
      *(uint2*)(b1base + (size_t)(dt * 16 + cl) * 2048 + m) = q;
    }
  }
}

// ---------------- phase C: (adj*256) @ z fp8 MFMA GEMM ----------------

template <int OUT_F32>
__global__ __launch_bounds__(256, 2) void gemm_adj(const unsigned char* __restrict__ adjf,
                                                   const unsigned char* __restrict__ Bt,
                                                   const unsigned short* __restrict__ biasT,
                                                   void* __restrict__ outp) {
  const int tid = threadIdx.x;
  const int lane = tid & 63;
  const int wid = tid >> 6;
  const int wr = wid >> 1, wc = wid & 1;
  const int orig = blockIdx.x;
  const int wg = (orig & 7) * 64 + (orig >> 3);
  const int b = wg >> 5;
  const int w32 = wg & 31;
  const int m0 = ((w32 >> 1) & 15) << 7;
  const int c0 = (w32 & 1) * 192;

  __shared__ __align__(16) unsigned char smem[81920];

  const unsigned char* aBase = adjf + ((size_t)b << 22);
  const unsigned char* bBase = Bt + (size_t)b * 786432;
  const int jx = ((tid & 7) ^ ((tid >> 3) & 7)) << 4;
  const unsigned char* gA = aBase + (size_t)(m0 + (tid >> 3)) * 2048 + jx;
  const unsigned char* gB = bBase + (size_t)(c0 + (tid >> 3)) * 2048 + jx;

  int aoff[2][4], boff[2][6];
#pragma unroll
  for (int kkp = 0; kkp < 2; ++kkp) {
    int c = ((lane >> 4) << 1) + kkp;
#pragma unroll
    for (int f = 0; f < 4; ++f) {
      int rA = wr * 64 + f * 16 + (lane & 15);
      aoff[kkp][f] = rA * 128 + ((c ^ (rA & 7)) << 4);
    }
#pragma unroll
    for (int n = 0; n < 6; ++n) {
      int rB = wc * 96 + n * 16 + (lane & 15);
      boff[kkp][n] = 16384 + rB * 128 + ((c ^ (rB & 7)) << 4);
    }
  }

  f32x4 acc[4][6] = {};

#define STAGE(BUF, KT)                                                               \
  {                                                                                  \
    _Pragma("unroll") for (int ii = 0; ii < 4; ++ii)                                 \
        gload16(gA + (size_t)ii * 65536 + (KT)*128, smem + (BUF) + ii * 4096 + tid * 16); \
    _Pragma("unroll") for (int ii = 0; ii < 6; ++ii)                                 \
        gload16(gB + (size_t)ii * 65536 + (KT)*128,                                  \
                smem + (BUF) + 16384 + ii * 4096 + tid * 16);                        \
  }

  STAGE(0, 0);

  int cur = 0;
  for (int kt = 0; kt < 16; ++kt) {
    const int nxt = cur ^ 40960;
    if (kt < 15) {
      STAGE(nxt, kt + 1);
      asm volatile("s_waitcnt vmcnt(10)" ::: "memory");
    } else {
      asm volatile("s_waitcnt vmcnt(0)" ::: "memory");
    }
    __builtin_amdgcn_s_barrier();
#pragma unroll
    for (int kkp = 0; kkp < 2; ++kkp) {
      ulong2 av[4], bv[6];
#pragma unroll
      for (int f = 0; f < 4; ++f) av[f] = *(const ulong2*)(smem + cur + aoff[kkp][f]);
#pragma unroll
      for (int n = 0; n < 6; ++n) bv[n] = *(const ulong2*)(smem + cur + boff[kkp][n]);
#pragma unroll
      for (int m = 0; m < 4; ++m)
#pragma unroll
        for (int n = 0; n < 6; ++n)
          acc[m][n] = __builtin_amdgcn_mfma_f32_16x16x32_fp8_fp8(
              (long)av[m].x, (long)bv[n].x, acc[m][n], 0, 0, 0);
#pragma unroll
      for (int m = 0; m < 4; ++m)
#pragma unroll
        for (int n = 0; n < 6; ++n)
          acc[m][n] = __builtin_amdgcn_mfma_f32_16x16x32_fp8_fp8(
              (long)av[m].y, (long)bv[n].y, acc[m][n], 0, 0, 0);
    }
    __builtin_amdgcn_s_barrier();
    cur = nxt;
  }
#undef STAGE

  const float inv256 = 0.00390625f;
  const int cl = lane & 15;
  const int r4 = (lane >> 4) << 2;
  const unsigned short* bi = biasT + (size_t)b * 786432;
  if (OUT_F32) {
    float* o = (float*)outp + (size_t)b * 786432;
#pragma unroll
    for (int m = 0; m < 4; ++m) {
      int row0 = m0 + wr * 64 + m * 16 + r4;
#pragma unroll
      for (int n = 0; n < 6; ++n) {
        int col = c0 + wc * 96 + n * 16 + cl;
        uint2 bw = *(const uint2*)(bi + ((size_t)col << 11) + row0);
        float bv0 = bf2f((unsigned short)(bw.x & 0xffff));
        float bv1 = bf2f((unsigned short)(bw.x >> 16));
        float bv2 = bf2f((unsigned short)(bw.y & 0xffff));
        float bv3 = bf2f((unsigned short)(bw.y >> 16));
        o[(size_t)(row0 + 0) * 384 + col] = acc[m][n][0] * inv256 + bv0;
        o[(size_t)(row0 + 1) * 384 + col] = acc[m][n][1] * inv256 + bv1;
        o[(size_t)(row0 + 2) * 384 + col] = acc[m][n][2] * inv256 + bv2;
        o[(size_t)(row0 + 3) * 384 + col] = acc[m][n][3] * inv256 + bv3;
      }
    }
  } else {
    unsigned char* o = (unsigned char*)outp + (size_t)b * 786432;
#pragma unroll
    for (int m = 0; m < 4; ++m) {
      int row0 = m0 + wr * 64 + m * 16 + r4;
      const int pb = ((row0 >> 7) << 7) + perm7(row0 & 127);
#pragma unroll
      for (int n = 0; n < 6; ++n) {
        int col = c0 + wc * 96 + n * 16 + cl;
        uint2 bw = *(const uint2*)(bi + ((size_t)col << 11) + row0);
        float v0 = acc[m][n][0] * inv256 + bf2f((unsigned short)(bw.x & 0xffff));
        float v1 = acc[m][n][1] * inv256 + bf2f((unsigned short)(bw.x >> 16));
        float v2 = acc[m][n][2] * inv256 + bf2f((unsigned short)(bw.y & 0xffff));
        float v3 = acc[m][n][3] * inv256 + bf2f((unsigned short)(bw.y >> 16));
        unsigned u = __builtin_amdgcn_cvt_pk_fp8_f32(v0, v1, 0, false);
        u = __builtin_amdgcn_cvt_pk_fp8_f32(v2, v3, (int)u, true);
        *(unsigned*)(o + (size_t)col * 2048 + pb) = u;
      }
    }
  }
}

// ---------------- launch ----------------

extern "C" void kernel_launch(void* const* d_in, const int* in_sizes, int n_in,
                              void* d_out, int out_size, void* d_ws, size_t ws_size,
                              hipStream_t stream) {
  const float* x = (const float*)d_in[0];
  const float* dis = (const float*)d_in[1];
  const float* K_S = (const float*)d_in[2];
  const float* V_S = (const float*)d_in[3];
  const float* K_T = (const float*)d_in[4];
  const float* V_T = (const float*)d_in[5];
  const float* W_Q0 = (const float*)d_in[6];
  const float* W_QS = (const float*)d_in[7];
  const float* W_QT = (const float*)d_in[8];
  const float* W2 = (const float*)d_in[9];
  const float* W_s0 = (const float*)d_in[10];
  const float* W_s1 = (const float*)d_in[11];

  char* ws = (char*)d_ws;
  float* pxmn = (float*)(ws + 0);                            //     98,304 B
  float* pqs = (float*)(ws + 98304);                         //  2,097,152 B
  unsigned short* ets_bf = (unsigned short*)(ws + 2195456);  //  1,048,576 B
  unsigned char* adjf = (unsigned char*)(ws + 3244032);      // 67,108,864 B
  unsigned char* z0Tf = (unsigned char*)(ws + 70352896);     // 12,582,912 B
  unsigned char* z1Tf = (unsigned char*)(ws + 82935808);     // 12,582,912 B
  unsigned short* bias0T = (unsigned short*)(ws + 95518720); // 25,165,824 B
  unsigned short* bias1T = (unsigned short*)(ws + 120684544);// 25,165,824 B
  float* at_g = (float*)(ws + 145850368);                    //        512 B

  k_xmn<<<768, 256, 0, stream>>>(x, pxmn);
  k_qs<<<512, 256, 0, stream>>>(x, W_Q0, W_QS, pqs);
  k_head<<<16, 256, 0, stream>>>(pqs, pxmn, W_Q0, W_QT, K_T, K_S, at_g);
  k_ets<<<128, 256, 0, stream>>>(at_g, V_T, V_S, ets_bf);
  k_adj<<<2048, 512, 0, stream>>>(ets_bf, dis, adjf);
  k_zb<<<768, 256, 0, stream>>>(x, W2, W_s0, W_s1, z0Tf, bias0T, bias1T);
  gemm_adj<0><<<512, 256, 0, stream>>>(adjf, z0Tf, bias0T, (void*)z1Tf);
  gemm_adj<1><<<512, 256, 0, stream>>>(adjf, z1Tf, bias1T, d_out);
}

// Round 12
// 197.648 us; speedup vs baseline: 2.6061x; 1.1744x over previous
//
#include <hip/hip_runtime.h>

typedef __bf16 bf16x8 __attribute__((ext_vector_type(8)));
typedef float f32x4 __attribute__((ext_vector_type(4)));

__device__ __forceinline__ unsigned short f2bf(float f) {
  unsigned u = __builtin_bit_cast(unsigned, f);
  u += 0x7fffu + ((u >> 16) & 1u);
  return (unsigned short)(u >> 16);
}
__device__ __forceinline__ float bf2f(unsigned short h) {
  unsigned u = ((unsigned)h) << 16;
  return __builtin_bit_cast(float, u);
}
__device__ __forceinline__ unsigned char f2fp8(float v) {
  return (unsigned char)(__builtin_amdgcn_cvt_pk_fp8_f32(v, v, 0, false) & 0xff);
}
__device__ __forceinline__ void gload16(const void* g, void* l) {
  __builtin_amdgcn_global_load_lds((const __attribute__((address_space(1))) void*)g,
                                   (__attribute__((address_space(3))) void*)l, 16, 0, 0);
}
// byte permutation within a 128-byte K-panel row: k = kk*32+g*8+e -> byte g*32+kk*8+e
__device__ __forceinline__ int perm7(int x) {
  return ((x >> 3) & 3) * 32 + ((x >> 5) << 3) + (x & 7);
}

// ---------------- phase A ----------------

// pxmn[c,b,t,k] = sum over n-chunk c of x[b,:,t,k]   (768 blocks = 3/CU)
__global__ __launch_bounds__(256) void k_xmn(const float* __restrict__ x,
                                             float* __restrict__ pxmn) {
  int bx = blockIdx.x;
  int b = bx / 48, r = bx % 48, t = r >> 2, c = r & 3;
  int k = threadIdx.x & 31, sl = threadIdx.x >> 5;
  const float* xp = x + (size_t)b * 786432 + (size_t)(c * 512) * 384 + (size_t)t * 32 + k;
  float s = 0.f;
  for (int i = 0; i < 64; ++i) s += xp[(size_t)((sl << 6) + i) * 384];
  __shared__ float red[8][32];
  red[sl][k] = s;
  __syncthreads();
  if (threadIdx.x < 32) {
    float tot = 0.f;
#pragma unroll
    for (int j = 0; j < 8; ++j) tot += red[j][threadIdx.x];
    pxmn[((c * 16 + b) * 12 + t) * 32 + threadIdx.x] = tot;
  }
}

// Per block (2 n-values): mean_t(x) -> @W_Q0 -> contract with 64 W_QS rows -> pqs[blk]
__global__ __launch_bounds__(256) void k_qs(const float* __restrict__ x,
                                            const float* __restrict__ W_Q0,
                                            const float* __restrict__ W_QS,
                                            float* __restrict__ pqs) {
  __shared__ __align__(16) float w0[1024];
  __shared__ __align__(16) float lm[1024];  // [b*2+n][k]
  __shared__ float lq[1024];                // [b*2+n][q]
  __shared__ float red[4][16][64];
  const int tid = threadIdx.x;
#pragma unroll
  for (int i = 0; i < 4; ++i) w0[tid + i * 256] = W_Q0[tid + i * 256];
  const int n0 = blockIdx.x * 2;

  // phase A: mean over t, float4 per thread: (b, n, k4)
  {
    const int b = tid >> 4, r = tid & 15, n = r >> 3, k4 = r & 7;
    const float4* xp = (const float4*)(x + ((size_t)(b * 2048 + n0 + n) * 12) * 32) + k4;
    float4 s0 = xp[0], s1 = xp[8], s2 = xp[16];
    float4 s3 = xp[24], s4 = xp[32], s5 = xp[40];
#pragma unroll
    for (int t = 6; t < 12; ++t) {
      float4 v = xp[t * 8];
      s0.x += v.x; s0.y += v.y; s0.z += v.z; s0.w += v.w;
      // rotate accumulator use to keep loads independent
      float4 tmp = s0; s0 = s1; s1 = s2; s2 = s3; s3 = s4; s4 = s5; s5 = tmp;
    }
    float4 m;
    m.x = (s0.x + s1.x + s2.x) + (s3.x + s4.x + s5.x);
    m.y = (s0.y + s1.y + s2.y) + (s3.y + s4.y + s5.y);
    m.z = (s0.z + s1.z + s2.z) + (s3.z + s4.z + s5.z);
    m.w = (s0.w + s1.w + s2.w) + (s3.w + s4.w + s5.w);
    const float inv12 = 1.0f / 12.0f;
    m.x *= inv12; m.y *= inv12; m.z *= inv12; m.w *= inv12;
    *(float4*)(lm + (b * 2 + n) * 32 + k4 * 4) = m;
  }
  __syncthreads();
  // phase B: lq = lm @ W_Q0
#pragma unroll
  for (int j = 0; j < 4; ++j) {
    int i = tid + j * 256;
    int bn = i >> 5, q = i & 31;
    const float* mrow = &lm[bn * 32];
    float a = 0.f;
#pragma unroll
    for (int k = 0; k < 32; ++k) a += mrow[k] * w0[k * 32 + q];
    lq[i] = a;
  }
  __syncthreads();
  // phase C: contract with W_QS rows [n0*32, n0*32+64)
  const int lane = tid & 63, w = tid >> 6;
  float acc[16];
#pragma unroll
  for (int b = 0; b < 16; ++b) acc[b] = 0.f;
#pragma unroll
  for (int rl = 0; rl < 16; ++rl) {
    int r = w * 16 + rl;
    float wv = W_QS[(size_t)(n0 * 32 + r) * 64 + lane];
#pragma unroll
    for (int b = 0; b < 16; ++b) acc[b] += lq[b * 64 + r] * wv;
  }
#pragma unroll
  for (int b = 0; b < 16; ++b) red[w][b][lane] = acc[b];
  __syncthreads();
#pragma unroll
  for (int it = 0; it < 4; ++it) {
    int idx = tid + it * 256;
    float s = red[0][idx >> 6][idx & 63] + red[1][idx >> 6][idx & 63] +
              red[2][idx >> 6][idx & 63] + red[3][idx >> 6][idx & 63];
    pqs[(size_t)blockIdx.x * 1024 + idx] = s;
  }
}

// Head-attention weights: pqs/pxmn reduce + qt + softmax -> at_g[16][8]
__global__ __launch_bounds__(256) void k_head(const float* __restrict__ pqs,
                                              const float* __restrict__ pxmn,
                                              const float* __restrict__ W_Q0,
                                              const float* __restrict__ W_QT,
                                              const float* __restrict__ K_T,
                                              const float* __restrict__ K_S,
                                              float* __restrict__ at_g) {
  const int b = blockIdx.x, tid = threadIdx.x;
  __shared__ float red[4][64];
  __shared__ float qs_s[64];
  __shared__ float xmn_s[384];
  __shared__ float xp[384];
  __shared__ float qtp[4][64];

  // pqs reduce over 1024 chunks: 4 independent accumulators
  {
    const int q = tid >> 6, dk = tid & 63;
    const float* p = pqs + (size_t)(q * 256) * 1024 + b * 64 + dk;
    float s0 = 0.f, s1 = 0.f, s2 = 0.f, s3 = 0.f;
#pragma unroll
    for (int c = 0; c < 256; c += 4) {
      s0 += p[(size_t)(c + 0) * 1024];
      s1 += p[(size_t)(c + 1) * 1024];
      s2 += p[(size_t)(c + 2) * 1024];
      s3 += p[(size_t)(c + 3) * 1024];
    }
    red[q][dk] = (s0 + s1) + (s2 + s3);
  }
  for (int i = tid; i < 384; i += 256) {
    float v = pxmn[(b * 12) * 32 + i] + pxmn[((16 + b) * 12) * 32 + i] +
              pxmn[((32 + b) * 12) * 32 + i] + pxmn[((48 + b) * 12) * 32 + i];
    xmn_s[i] = v * (1.0f / 2048.0f);
  }
  __syncthreads();
  for (int i = tid; i < 384; i += 256) {
    int t = i >> 5, q = i & 31;
    float a = 0.f;
#pragma unroll
    for (int k = 0; k < 32; ++k) a += xmn_s[t * 32 + k] * W_Q0[k * 32 + q];
    xp[i] = a;
  }
  if (tid < 64) qs_s[tid] = red[0][tid] + red[1][tid] + red[2][tid] + red[3][tid];
  __syncthreads();
  {
    const int w = tid >> 6, dk = tid & 63;
    const float* wq = W_QT + (size_t)(w * 96) * 64 + dk;
    const float* xw = xp + w * 96;
    float a0 = 0.f, a1 = 0.f, a2 = 0.f;
#pragma unroll
    for (int i = 0; i < 96; i += 3) {
      a0 += xw[i + 0] * wq[(size_t)(i + 0) * 64];
      a1 += xw[i + 1] * wq[(size_t)(i + 1) * 64];
      a2 += xw[i + 2] * wq[(size_t)(i + 2) * 64];
    }
    qtp[w][dk] = (a0 + a1) + a2;
  }
  __syncthreads();
  if (tid < 64) {
    int lane = tid;
    float qtv = qtp[0][lane] + qtp[1][lane] + qtp[2][lane] + qtp[3][lane];
    float qsv = qs_s[lane];
    float lt[4], ls[4];
#pragma unroll
    for (int h = 0; h < 4; ++h) {
      float p = qtv * K_T[h * 64 + lane];
#pragma unroll
      for (int off = 32; off > 0; off >>= 1) p += __shfl_xor(p, off);
      lt[h] = p;
      float p2 = qsv * K_S[h * 64 + lane];
#pragma unroll
      for (int off = 32; off > 0; off >>= 1) p2 += __shfl_xor(p2, off);
      ls[h] = p2;
    }
    if (lane == 0) {
      const float scale = 0.125f;
      float mt = fmaxf(fmaxf(lt[0], lt[1]), fmaxf(lt[2], lt[3]));
      float ms = fmaxf(fmaxf(ls[0], ls[1]), fmaxf(ls[2], ls[3]));
      float et[4], es[4], st = 0.f, ss = 0.f;
#pragma unroll
      for (int h = 0; h < 4; ++h) {
        et[h] = __expf((lt[h] - mt) * scale); st += et[h];
        es[h] = __expf((ls[h] - ms) * scale); ss += es[h];
      }
#pragma unroll
      for (int h = 0; h < 4; ++h) {
        at_g[b * 8 + h] = et[h] / st;
        at_g[b * 8 + 4 + h] = es[h] / ss;
      }
    }
  }
}

// ets_bf[b][n][16] (k>=10 zero) from attention-mixed V  (128 blocks)
__global__ __launch_bounds__(256) void k_ets(const float* __restrict__ at_g,
                                             const float* __restrict__ V_T,
                                             const float* __restrict__ V_S,
                                             unsigned short* __restrict__ ets_bf) {
  int idx = blockIdx.x * 256 + threadIdx.x;
  int b = idx >> 11, n = idx & 2047;
  const float* at = at_g + b * 8;
  float a0 = at[0], a1 = at[1], a2 = at[2], a3 = at[3];
  float s0 = at[4], s1 = at[5], s2 = at[6], s3 = at[7];
  float v[10];
#pragma unroll
  for (int c = 0; c < 10; ++c) {
    int o = n * 10 + c;
    v[c] = a0 * V_T[o] + a1 * V_T[20480 + o] + a2 * V_T[40960 + o] + a3 * V_T[61440 + o] +
           s0 * V_S[o] + s1 * V_S[20480 + o] + s2 * V_S[40960 + o] + s3 * V_S[61440 + o];
  }
  uint4 lo, hi;
  lo.x = (unsigned)f2bf(v[0]) | ((unsigned)f2bf(v[1]) << 16);
  lo.y = (unsigned)f2bf(v[2]) | ((unsigned)f2bf(v[3]) << 16);
  lo.z = (unsigned)f2bf(v[4]) | ((unsigned)f2bf(v[5]) << 16);
  lo.w = (unsigned)f2bf(v[6]) | ((unsigned)f2bf(v[7]) << 16);
  hi.x = (unsigned)f2bf(v[8]) | ((unsigned)f2bf(v[9]) << 16);
  hi.y = 0; hi.z = 0; hi.w = 0;
  *(uint4*)(ets_bf + (size_t)idx * 16) = lo;
  *(uint4*)(ets_bf + (size_t)idx * 16 + 8) = hi;
}

// ---------------- phase B: MFMA adjacency + row softmax -> fp8 (x256, k-permuted) -----

__global__ __launch_bounds__(512, 4) void k_adj(const unsigned short* __restrict__ ets_bf,
                                                const float* __restrict__ dis,
                                                unsigned char* __restrict__ adjf) {
  __shared__ __align__(16) unsigned char Bsh[65536];
  __shared__ float st_max[8][16];
  __shared__ float st_sum[8][16];
  __shared__ float rowmax_s[16];
  __shared__ float rowinv_s[16];

  const int tid = threadIdx.x;
  const int lane = tid & 63;
  const int w = tid >> 6;
  const int cl = lane & 15;
  const int g = lane >> 4;
  const int b = blockIdx.x >> 7;
  const int n0 = (blockIdx.x & 127) << 4;

  const unsigned char* gsrc = (const unsigned char*)(ets_bf + (size_t)b * 32768);
#pragma unroll
  for (int it = 0; it < 8; ++it)
    gload16(gsrc + it * 8192 + tid * 16, Bsh + it * 8192 + (w << 10));
  __syncthreads();

  uint4 araw = *(const uint4*)(ets_bf + ((size_t)b * 2048 + n0 + cl) * 16 + (g & 1) * 8);
  if (g >= 2) { araw.x = 0; araw.y = 0; araw.z = 0; araw.w = 0; }
  bf16x8 afrag = __builtin_bit_cast(bf16x8, araw);

  f32x4 acc[16];
  const int cbase = (w << 8) + cl;
#pragma unroll
  for (int n = 0; n < 16; ++n) {
    uint4 braw = *(const uint4*)(Bsh + (size_t)(cbase + n * 16) * 32 + (g & 1) * 16);
    if (g >= 2) { braw.x = 0; braw.y = 0; braw.z = 0; braw.w = 0; }
    bf16x8 bfrag = __builtin_bit_cast(bf16x8, braw);
    acc[n] = __builtin_amdgcn_mfma_f32_16x16x32_bf16(afrag, bfrag, (f32x4){0.f, 0.f, 0.f, 0.f},
                                                     0, 0, 0);
  }

  float mx[4] = {-1e30f, -1e30f, -1e30f, -1e30f};
  const float* dbase = dis + (size_t)(n0 + g * 4) * 2048 + (w << 8) + cl;
#pragma unroll
  for (int n = 0; n < 16; ++n) {
#pragma unroll
    for (int j = 0; j < 4; ++j) {
      float s = fmaxf(acc[n][j] + dbase[(size_t)j * 2048 + n * 16], 0.f);
      acc[n][j] = s;
      mx[j] = fmaxf(mx[j], s);
    }
  }
#pragma unroll
  for (int j = 0; j < 4; ++j) {
    mx[j] = fmaxf(mx[j], __shfl_xor(mx[j], 1));
    mx[j] = fmaxf(mx[j], __shfl_xor(mx[j], 2));
    mx[j] = fmaxf(mx[j], __shfl_xor(mx[j], 4));
    mx[j] = fmaxf(mx[j], __shfl_xor(mx[j], 8));
  }
  if (cl == 0) {
#pragma unroll
    for (int j = 0; j < 4; ++j) st_max[w][g * 4 + j] = mx[j];
  }
  __syncthreads();
  if (tid < 16) {
    float m = st_max[0][tid];
#pragma unroll
    for (int ww = 1; ww < 8; ++ww) m = fmaxf(m, st_max[ww][tid]);
    rowmax_s[tid] = m;
  }
  __syncthreads();

  float rm[4], sm[4] = {0.f, 0.f, 0.f, 0.f};
#pragma unroll
  for (int j = 0; j < 4; ++j) rm[j] = rowmax_s[g * 4 + j];
#pragma unroll
  for (int n = 0; n < 16; ++n) {
#pragma unroll
    for (int j = 0; j < 4; ++j) {
      float e = __expf(acc[n][j] - rm[j]);
      acc[n][j] = e;
      sm[j] += e;
    }
  }
#pragma unroll
  for (int j = 0; j < 4; ++j) {
    sm[j] += __shfl_xor(sm[j], 1);
    sm[j] += __shfl_xor(sm[j], 2);
    sm[j] += __shfl_xor(sm[j], 4);
    sm[j] += __shfl_xor(sm[j], 8);
  }
  if (cl == 0) {
#pragma unroll
    for (int j = 0; j < 4; ++j) st_sum[w][g * 4 + j] = sm[j];
  }
  __syncthreads();
  if (tid < 16) {
    float s = st_sum[0][tid];
#pragma unroll
    for (int ww = 1; ww < 8; ++ww) s += st_sum[ww][tid];
    rowinv_s[tid] = 256.0f / s;  // x256 so fp8 stays in normal range
  }
  __syncthreads();  // all Bsh B-reads done -> safe to reuse as transpose buf

  unsigned char* Tw = Bsh + (w << 12);
  float inv[4];
#pragma unroll
  for (int j = 0; j < 4; ++j) inv[j] = rowinv_s[g * 4 + j];
#pragma unroll
  for (int n = 0; n < 16; ++n) {
    int ml = n * 16 + cl;
    int pb = ((ml >> 7) << 7) + perm7(ml & 127);
#pragma unroll
    for (int j = 0; j < 4; ++j)
      Tw[(g * 4 + j) * 256 + pb] = f2fp8(acc[n][j] * inv[j]);
  }
  __syncthreads();

  unsigned char* obase = adjf + ((size_t)b * 2048 + n0) * 2048 + (w << 8);
#pragma unroll
  for (int r = 0; r < 16; ++r) {
    unsigned v = *(const unsigned*)(Tw + r * 256 + lane * 4);
    *(unsigned*)(obase + (size_t)r * 2048 + lane * 4) = v;
  }
}

// ---------------- phase C producer: MFMA x @ {W2,Ws0,Ws1} ----------------

__global__ __launch_bounds__(256) void k_zb(const float* __restrict__ x,
                                            const float* __restrict__ W2,
                                            const float* __restrict__ Ws0,
                                            const float* __restrict__ Ws1,
                                            unsigned char* __restrict__ z0Tf,
                                            unsigned short* __restrict__ bias0T,
                                            unsigned short* __restrict__ bias1T) {
  __shared__ __align__(16) unsigned short wlds[3072];  // [mat*32+d][k] bf16
  const int tid = threadIdx.x;
  for (int j = tid; j < 3072; j += 256) {
    int mat = j >> 10, r = j & 1023, k = r >> 5, d = r & 31;
    const float* Wsrc = (mat == 0) ? W2 : (mat == 1 ? Ws0 : Ws1);
    wlds[(mat * 32 + d) * 32 + k] = f2bf(Wsrc[r]);
  }
  __syncthreads();

  const int lane = tid & 63, w = tid >> 6;
  const int cl = lane & 15, g = lane >> 4;
  const int bx = blockIdx.x;
  const int b = bx / 48, r = bx % 48, t = r >> 2, mc = r & 3;
  const int m0w = mc * 512 + w * 128;

  bf16x8 bfr[6];
#pragma unroll
  for (int dt = 0; dt < 6; ++dt)
    bfr[dt] = *(const bf16x8*)(wlds + (dt * 16 + cl) * 32 + g * 8);

  const float* gx = x + ((size_t)(b * 2048 + m0w + cl) * 12 + t) * 32 + g * 8;
  unsigned char* z0base = z0Tf + (size_t)b * 786432 + (size_t)(t * 32) * 2048;
  unsigned short* b0base = bias0T + (size_t)b * 786432 + (size_t)(t * 32) * 2048;
  unsigned short* b1base = bias1T + (size_t)b * 786432 + (size_t)(t * 32) * 2048;

#pragma unroll
  for (int i = 0; i < 8; ++i) {
    const float* xp = gx + (size_t)i * 16 * 384;
    float4 v0 = *(const float4*)xp;
    float4 v1 = *(const float4*)(xp + 4);
    bf16x8 af;
    af[0] = (__bf16)v0.x; af[1] = (__bf16)v0.y; af[2] = (__bf16)v0.z; af[3] = (__bf16)v0.w;
    af[4] = (__bf16)v1.x; af[5] = (__bf16)v1.y; af[6] = (__bf16)v1.z; af[7] = (__bf16)v1.w;
    f32x4 acc[6];
#pragma unroll
    for (int dt = 0; dt < 6; ++dt)
      acc[dt] = __builtin_amdgcn_mfma_f32_16x16x32_bf16(af, bfr[dt],
                                                        (f32x4){0.f, 0.f, 0.f, 0.f}, 0, 0, 0);
    const int m = m0w + i * 16 + g * 4;
    const int pb = ((m >> 7) << 7) + perm7(m & 127);
#pragma unroll
    for (int dt = 0; dt < 2; ++dt) {
      unsigned u = __builtin_amdgcn_cvt_pk_fp8_f32(acc[dt][0], acc[dt][1], 0, false);
      u = __builtin_amdgcn_cvt_pk_fp8_f32(acc[dt][2], acc[dt][3], (int)u, true);
      *(unsigned*)(z0base + (size_t)(dt * 16 + cl) * 2048 + pb) = u;
    }
#pragma unroll
    for (int dt = 0; dt < 2; ++dt) {
      uint2 p;
      p.x = (unsigned)f2bf(acc[2 + dt][0]) | ((unsigned)f2bf(acc[2 + dt][1]) << 16);
      p.y = (unsigned)f2bf(acc[2 + dt][2]) | ((unsigned)f2bf(acc[2 + dt][3]) << 16);
      *(uint2*)(b0base + (size_t)(dt * 16 + cl) * 2048 + m) = p;
      uint2 q;
      q.x = (unsigned)f2bf(acc[4 + dt][0]) | ((unsigned)f2bf(acc[4 + dt][1]) << 16);
      q.y = (unsigned)f2bf(acc[4 + dt][2]) | ((unsigned)f2bf(acc[4 + dt][3]) << 16);
      *(uint2*)(b1base + (size_t)(dt * 16 + cl) * 2048 + m) = q;
    }
  }
}

// ---------------- phase C: (adj*256) @ z fp8 MFMA GEMM ----------------

template <int OUT_F32>
__global__ __launch_bounds__(256, 2) void gemm_adj(const unsigned char* __restrict__ adjf,
                                                   const unsigned char* __restrict__ Bt,
                                                   const unsigned short* __restrict__ biasT,
                                                   void* __restrict__ outp) {
  const int tid = threadIdx.x;
  const int lane = tid & 63;
  const int wid = tid >> 6;
  const int wr = wid >> 1, wc = wid & 1;
  const int orig = blockIdx.x;
  const int wg = (orig & 7) * 64 + (orig >> 3);
  const int b = wg >> 5;
  const int w32 = wg & 31;
  const int m0 = ((w32 >> 1) & 15) << 7;
  const int c0 = (w32 & 1) * 192;

  __shared__ __align__(16) unsigned char smem[81920];

  const unsigned char* aBase = adjf + ((size_t)b << 22);
  const unsigned char* bBase = Bt + (size_t)b * 786432;
  const int jx = ((tid & 7) ^ ((tid >> 3) & 7)) << 4;
  const unsigned char* gA = aBase + (size_t)(m0 + (tid >> 3)) * 2048 + jx;
  const unsigned char* gB = bBase + (size_t)(c0 + (tid >> 3)) * 2048 + jx;

  int aoff[2][4], boff[2][6];
#pragma unroll
  for (int kkp = 0; kkp < 2; ++kkp) {
    int c = ((lane >> 4) << 1) + kkp;
#pragma unroll
    for (int f = 0; f < 4; ++f) {
      int rA = wr * 64 + f * 16 + (lane & 15);
      aoff[kkp][f] = rA * 128 + ((c ^ (rA & 7)) << 4);
    }
#pragma unroll
    for (int n = 0; n < 6; ++n) {
      int rB = wc * 96 + n * 16 + (lane & 15);
      boff[kkp][n] = 16384 + rB * 128 + ((c ^ (rB & 7)) << 4);
    }
  }

  f32x4 acc[4][6] = {};

#define STAGE(BUF, KT)                                                               \
  {                                                                                  \
    _Pragma("unroll") for (int ii = 0; ii < 4; ++ii)                                 \
        gload16(gA + (size_t)ii * 65536 + (KT)*128, smem + (BUF) + ii * 4096 + tid * 16); \
    _Pragma("unroll") for (int ii = 0; ii < 6; ++ii)                                 \
        gload16(gB + (size_t)ii * 65536 + (KT)*128,                                  \
                smem + (BUF) + 16384 + ii * 4096 + tid * 16);                        \
  }

  STAGE(0, 0);

  int cur = 0;
  for (int kt = 0; kt < 16; ++kt) {
    const int nxt = cur ^ 40960;
    if (kt < 15) {
      STAGE(nxt, kt + 1);
      asm volatile("s_waitcnt vmcnt(10)" ::: "memory");
    } else {
      asm volatile("s_waitcnt vmcnt(0)" ::: "memory");
    }
    __builtin_amdgcn_s_barrier();
#pragma unroll
    for (int kkp = 0; kkp < 2; ++kkp) {
      ulong2 av[4], bv[6];
#pragma unroll
      for (int f = 0; f < 4; ++f) av[f] = *(const ulong2*)(smem + cur + aoff[kkp][f]);
#pragma unroll
      for (int n = 0; n < 6; ++n) bv[n] = *(const ulong2*)(smem + cur + boff[kkp][n]);
#pragma unroll
      for (int m = 0; m < 4; ++m)
#pragma unroll
        for (int n = 0; n < 6; ++n)
          acc[m][n] = __builtin_amdgcn_mfma_f32_16x16x32_fp8_fp8(
              (long)av[m].x, (long)bv[n].x, acc[m][n], 0, 0, 0);
#pragma unroll
      for (int m = 0; m < 4; ++m)
#pragma unroll
        for (int n = 0; n < 6; ++n)
          acc[m][n] = __builtin_amdgcn_mfma_f32_16x16x32_fp8_fp8(
              (long)av[m].y, (long)bv[n].y, acc[m][n], 0, 0, 0);
    }
    __builtin_amdgcn_s_barrier();
    cur = nxt;
  }
#undef STAGE

  const float inv256 = 0.00390625f;
  const int cl = lane & 15;
  const int r4 = (lane >> 4) << 2;
  const unsigned short* bi = biasT + (size_t)b * 786432;
  if (OUT_F32) {
    float* o = (float*)outp + (size_t)b * 786432;
#pragma unroll
    for (int m = 0; m < 4; ++m) {
      int row0 = m0 + wr * 64 + m * 16 + r4;
#pragma unroll
      for (int n = 0; n < 6; ++n) {
        int col = c0 + wc * 96 + n * 16 + cl;
        uint2 bw = *(const uint2*)(bi + ((size_t)col << 11) + row0);
        float bv0 = bf2f((unsigned short)(bw.x & 0xffff));
        float bv1 = bf2f((unsigned short)(bw.x >> 16));
        float bv2 = bf2f((unsigned short)(bw.y & 0xffff));
        float bv3 = bf2f((unsigned short)(bw.y >> 16));
        o[(size_t)(row0 + 0) * 384 + col] = acc[m][n][0] * inv256 + bv0;
        o[(size_t)(row0 + 1) * 384 + col] = acc[m][n][1] * inv256 + bv1;
        o[(size_t)(row0 + 2) * 384 + col] = acc[m][n][2] * inv256 + bv2;
        o[(size_t)(row0 + 3) * 384 + col] = acc[m][n][3] * inv256 + bv3;
      }
    }
  } else {
    unsigned char* o = (unsigned char*)outp + (size_t)b * 786432;
#pragma unroll
    for (int m = 0; m < 4; ++m) {
      int row0 = m0 + wr * 64 + m * 16 + r4;
      const int pb = ((row0 >> 7) << 7) + perm7(row0 & 127);
#pragma unroll
      for (int n = 0; n < 6; ++n) {
        int col = c0 + wc * 96 + n * 16 + cl;
        uint2 bw = *(const uint2*)(bi + ((size_t)col << 11) + row0);
        float v0 = acc[m][n][0] * inv256 + bf2f((unsigned short)(bw.x & 0xffff));
        float v1 = acc[m][n][1] * inv256 + bf2f((unsigned short)(bw.x >> 16));
        float v2 = acc[m][n][2] * inv256 + bf2f((unsigned short)(bw.y & 0xffff));
        float v3 = acc[m][n][3] * inv256 + bf2f((unsigned short)(bw.y >> 16));
        unsigned u = __builtin_amdgcn_cvt_pk_fp8_f32(v0, v1, 0, false);
        u = __builtin_amdgcn_cvt_pk_fp8_f32(v2, v3, (int)u, true);
        *(unsigned*)(o + (size_t)col * 2048 + pb) = u;
      }
    }
  }
}

// ---------------- launch ----------------

extern "C" void kernel_launch(void* const* d_in, const int* in_sizes, int n_in,
                              void* d_out, int out_size, void* d_ws, size_t ws_size,
                              hipStream_t stream) {
  const float* x = (const float*)d_in[0];
  const float* dis = (const float*)d_in[1];
  const float* K_S = (const float*)d_in[2];
  const float* V_S = (const float*)d_in[3];
  const float* K_T = (const float*)d_in[4];
  const float* V_T = (const float*)d_in[5];
  const float* W_Q0 = (const float*)d_in[6];
  const float* W_QS = (const float*)d_in[7];
  const float* W_QT = (const float*)d_in[8];
  const float* W2 = (const float*)d_in[9];
  const float* W_s0 = (const float*)d_in[10];
  const float* W_s1 = (const float*)d_in[11];

  char* ws = (char*)d_ws;
  float* pxmn = (float*)(ws + 0);                            //     98,304 B
  float* pqs = (float*)(ws + 98304);                         //  4,194,304 B
  unsigned short* ets_bf = (unsigned short*)(ws + 4292608);  //  1,048,576 B
  unsigned char* adjf = (unsigned char*)(ws + 5341184);      // 67,108,864 B
  unsigned char* z0Tf = (unsigned char*)(ws + 72450048);     // 12,582,912 B
  unsigned char* z1Tf = (unsigned char*)(ws + 85032960);     // 12,582,912 B
  unsigned short* bias0T = (unsigned short*)(ws + 97615872); // 25,165,824 B
  unsigned short* bias1T = (unsigned short*)(ws + 122781696);// 25,165,824 B
  float* at_g = (float*)(ws + 147947520);                    //        512 B

  k_xmn<<<768, 256, 0, stream>>>(x, pxmn);
  k_qs<<<1024, 256, 0, stream>>>(x, W_Q0, W_QS, pqs);
  k_head<<<16, 256, 0, stream>>>(pqs, pxmn, W_Q0, W_QT, K_T, K_S, at_g);
  k_ets<<<128, 256, 0, stream>>>(at_g, V_T, V_S, ets_bf);
  k_adj<<<2048, 512, 0, stream>>>(ets_bf, dis, adjf);
  k_zb<<<768, 256, 0, stream>>>(x, W2, W_s0, W_s1, z0Tf, bias0T, bias1T);
  gemm_adj<0><<<512, 256, 0, stream>>>(adjf, z0Tf, bias0T, (void*)z1Tf);
  gemm_adj<1><<<512, 256, 0, stream>>>(adjf, z1Tf, bias1T, d_out);
}